// Round 2
// 957.493 us; speedup vs baseline: 1.1858x; 1.1858x over previous
//
#include <hip/hip_runtime.h>
#include <hip/hip_bf16.h>

#define N_NODES 50000
#define N_EDGES 800000
#define IN_CH   256
#define EDGE_DIM 32
#define NH 4
#define NC 32
#define HC 128   // NH*NC
#define SCAN_N 50176   // 196 * 256 >= N_NODES

// hw transcendentals (avoid __exp2f/__log2f: glibc math.h name collision)
__device__ __forceinline__ float fexp2(float x) { return __builtin_amdgcn_exp2f(x); }
__device__ __forceinline__ float flog2(float x) { return __builtin_amdgcn_logf(x); }
__device__ __forceinline__ float fexp(float x)  { return __builtin_amdgcn_exp2f(x * 1.44269504089f); }

// Dual-dtype scalar load: f32 flag selects fp32 vs bf16 interpretation of the raw buffer.
__device__ __forceinline__ float ldf(const void* p, long i, bool f32) {
    return f32 ? ((const float*)p)[i]
               : __bfloat162float(((const __hip_bfloat16*)p)[i]);
}

// Dual-width index loads: idx64 => buffer is int64 [2,E] (values < 2^31, read low words).
__device__ __forceinline__ int ld_src(const int* ei, long e, bool idx64) {
    return idx64 ? ei[2 * e] : ei[e];
}
__device__ __forceinline__ int ld_dst(const int* ei, long e, bool idx64) {
    return idx64 ? ei[2 * ((long)N_EDGES + e)] : ei[(long)N_EDGES + e];
}

// fast tanh: 1 - 2/(e^{2x}+1); exact saturation at +/-inf, ~1e-7 abs err
__device__ __forceinline__ float ftanh(float x) {
    const float e = fexp2(x * 2.88539008178f);   // 2*log2(e)
    return 1.0f - 2.0f * __builtin_amdgcn_rcpf(e + 1.0f);
}

// ---------------- dtype detection (runs every call, deterministic) ----------------
__global__ __launch_bounds__(256) void detect_k(const unsigned short* __restrict__ xu,
                                                const int* __restrict__ ei,
                                                int* __restrict__ flag) {
    __shared__ int zc, bc, nz_idx;
    if (threadIdx.x == 0) { zc = 0; bc = 0; nz_idx = 0; }
    __syncthreads();
    int z = 0, b = 0, hi = 0;
    for (int i = threadIdx.x; i < 16384; i += 256) {
        const unsigned short w = xu[2 * i];
        if (w == 0) ++z;
        if ((w & 0x7F80) == 0x7F80) ++b;
    }
    for (int i = threadIdx.x; i < 8192; i += 256)
        if (ei[2 * i + 1] != 0) hi = 1;
    atomicAdd(&zc, z);
    atomicAdd(&bc, b);
    if (hi) atomicAdd(&nz_idx, 1);
    __syncthreads();
    if (threadIdx.x == 0) {
        flag[0] = (zc > 8192 || bc > 0) ? 1 : 0;  // 1 => fp32 float buffers
        flag[1] = (nz_idx == 0) ? 1 : 0;          // 1 => int64 indices
    }
}

// ---------------- CSR build ----------------
__global__ __launch_bounds__(256) void zero_deg_k(int* __restrict__ deg) {
    const int i = blockIdx.x * 256 + threadIdx.x;
    if (i < N_NODES) deg[i] = 0;
}

__global__ __launch_bounds__(256) void hist_k(const int* __restrict__ ei,
                                              const int* __restrict__ flag,
                                              int* __restrict__ deg) {
    const bool idx64 = (flag[1] != 0);
    const long e = (long)blockIdx.x * 256 + threadIdx.x;
    if (e < N_EDGES) atomicAdd(&deg[ld_dst(ei, e, idx64)], 1);
}

// single-block exclusive scan: deg[0..N) -> row_ptr[0..N], cursor copy
__global__ __launch_bounds__(256) void scan_k(const int* __restrict__ deg,
                                              int* __restrict__ row_ptr,
                                              int* __restrict__ cursor) {
    __shared__ int wsum[4];
    __shared__ int s_carry;
    const int tid = threadIdx.x;
    const int lane = tid & 63, wid = tid >> 6;
    if (tid == 0) s_carry = 0;
    __syncthreads();
    for (int base = 0; base < SCAN_N; base += 256) {
        const int i = base + tid;
        const int v = (i < N_NODES) ? deg[i] : 0;
        int x = v;
        #pragma unroll
        for (int off = 1; off < 64; off <<= 1) {
            const int t = __shfl_up(x, off);
            if (lane >= off) x += t;
        }
        if (lane == 63) wsum[wid] = x;
        __syncthreads();
        int wpre = 0;
        for (int w = 0; w < wid; ++w) wpre += wsum[w];
        const int total = wsum[0] + wsum[1] + wsum[2] + wsum[3];
        const int excl = s_carry + wpre + x - v;
        if (i < N_NODES) { row_ptr[i] = excl; cursor[i] = excl; }
        __syncthreads();
        if (tid == 0) s_carry += total;
        __syncthreads();
    }
    if (tid == 0) row_ptr[N_NODES] = s_carry;
}

__global__ __launch_bounds__(256) void scatter_k(const int* __restrict__ ei,
                                                 const int* __restrict__ flag,
                                                 int* __restrict__ cursor,
                                                 int* __restrict__ eids,
                                                 int* __restrict__ esrc) {
    const bool idx64 = (flag[1] != 0);
    const long e = (long)blockIdx.x * 256 + threadIdx.x;
    if (e >= N_EDGES) return;
    const int dst = ld_dst(ei, e, idx64);
    const int src = ld_src(ei, e, idx64);
    const int pos = atomicAdd(&cursor[dst], 1);
    eids[pos] = (int)e;
    esrc[pos] = src;
}

// ---------------- node GEMMs: x_src = x@W_src, x_dst = x@W_dst ----------------
__global__ __launch_bounds__(256) void node_gemm_k(const void* __restrict__ x,
                                                   const void* __restrict__ Wsrc,
                                                   const void* __restrict__ Wdst,
                                                   const int* __restrict__ flag,
                                                   float* __restrict__ xsrc,
                                                   float* __restrict__ xdst) {
    const bool f32 = (flag[0] != 0);
    __shared__ float sx[8][IN_CH];
    const int tid = threadIdx.x;
    const long n0 = (long)blockIdx.x * 8;
    #pragma unroll
    for (int r = 0; r < 8; ++r)
        sx[r][tid] = ldf(x, (n0 + r) * IN_CH + tid, f32);
    __syncthreads();

    const int mat = tid >> 7;
    const int col = tid & 127;
    const void* __restrict__ W = mat ? Wdst : Wsrc;
    float acc[8] = {0,0,0,0,0,0,0,0};
    for (int k = 0; k < IN_CH; k += 4) {
        const float w0 = ldf(W, (long)(k + 0) * HC + col, f32);
        const float w1 = ldf(W, (long)(k + 1) * HC + col, f32);
        const float w2 = ldf(W, (long)(k + 2) * HC + col, f32);
        const float w3 = ldf(W, (long)(k + 3) * HC + col, f32);
        #pragma unroll
        for (int r = 0; r < 8; ++r) {
            const float4 sv = *(const float4*)&sx[r][k];
            acc[r] += sv.x * w0 + sv.y * w1 + sv.z * w2 + sv.w * w3;
        }
    }
    float* __restrict__ o = mat ? xdst : xsrc;
    #pragma unroll
    for (int r = 0; r < 8; ++r)
        o[(n0 + r) * HC + col] = acc[r];
}

// ---------------- edge alpha pass: one edge per wave, W_edge in registers ----------------
// lane l owns channels {2l, 2l+1}; head h = l>>4.
// W_edge slice per lane = 32 float2 (64 VGPR), loaded ONCE per persistent block.
// sea slices are wave-private -> no __syncthreads in the loop.
__global__ __launch_bounds__(256) void edge_alpha_k(const int* __restrict__ ei,
                                                    const void* __restrict__ eattr,
                                                    const void* __restrict__ dw,
                                                    const void* __restrict__ Wedge,
                                                    const void* __restrict__ att,
                                                    const void* __restrict__ sscale,
                                                    const int* __restrict__ flag,
                                                    const float* __restrict__ xsrc,
                                                    const float* __restrict__ xdst,
                                                    float* __restrict__ ea_ws,
                                                    float* __restrict__ araw_out) {
    const bool f32   = (flag[0] != 0);
    const bool idx64 = (flag[1] != 0);
    __shared__ float sea[4][EDGE_DIM];   // one 32-float slice per wave (wave-private)

    const int tid = threadIdx.x;
    const int l   = tid & 63;            // lane
    const int wid = tid >> 6;            // wave in block
    const int h   = l >> 4;              // head owned at reduce root

    // W_edge columns {2l, 2l+1} into registers (once per block)
    float2 wreg[EDGE_DIM];
    float2 att2;
    if (f32) {
        const float2* W2 = (const float2*)Wedge;
        #pragma unroll
        for (int k = 0; k < EDGE_DIM; ++k) wreg[k] = W2[(long)k * 64 + l];
        att2 = ((const float2*)att)[l];
    } else {
        const unsigned int* Wb = (const unsigned int*)Wedge;  // 2 bf16 per word
        #pragma unroll
        for (int k = 0; k < EDGE_DIM; ++k) {
            const unsigned int u = Wb[k * 64 + l];
            wreg[k].x = __uint_as_float(u << 16);
            wreg[k].y = __uint_as_float(u & 0xffff0000u);
        }
        const unsigned int ua = ((const unsigned int*)att)[l];
        att2.x = __uint_as_float(ua << 16);
        att2.y = __uint_as_float(ua & 0xffff0000u);
    }
    const float ss = ldf(sscale, h, f32);

    const long ngroups = N_EDGES / 4;    // 4 edges (waves) per block iteration
    for (long g = blockIdx.x; g < ngroups; g += (long)gridDim.x) {
        const long e = g * 4 + wid;
        const int src = ld_src(ei, e, idx64);
        const int dst = ld_dst(ei, e, idx64);
        const float dwv = ldf(dw, e, f32);
        if (l < EDGE_DIM) sea[wid][l] = ldf(eattr, e * EDGE_DIM + l, f32);
        __builtin_amdgcn_wave_barrier();  // keep LDS write before reads (wave-private slice)

        // e_feat for the 2 owned channels
        float ef0 = 0.0f, ef1 = 0.0f;
        #pragma unroll
        for (int k = 0; k < EDGE_DIM; k += 4) {
            const float4 a = *(const float4*)&sea[wid][k];   // broadcast read
            ef0 += a.x * wreg[k].x + a.y * wreg[k+1].x + a.z * wreg[k+2].x + a.w * wreg[k+3].x;
            ef1 += a.x * wreg[k].y + a.y * wreg[k+1].y + a.z * wreg[k+2].y + a.w * wreg[k+3].y;
        }

        const float2 xs = *(const float2*)(xsrc + (long)src * HC + 2 * l);
        const float2 xd = *(const float2*)(xdst + (long)dst * HC + 2 * l);
        float p = ftanh(xs.x + xd.x + ef0) * att2.x
                + ftanh(xs.y + xd.y + ef1) * att2.y;

        // sum the 16 lanes of each head
        p += __shfl_down(p, 8, 16);
        p += __shfl_down(p, 4, 16);
        p += __shfl_down(p, 2, 16);
        p += __shfl_down(p, 1, 16);

        if ((l & 15) == 0) {
            araw_out[e * 4 + h] = p;                          // pre-decay logit
            const float d = fexp2(ss * flog2(dwv));           // dwv ** ss
            ea_ws[e * 4 + h] = fexp(p * d);
        }
        __builtin_amdgcn_wave_barrier();
    }
}

// ---------------- CSR aggregation: one wave per dst node, no atomics ----------------
// lane owns channels {2*lane, 2*lane+1}; head h = lane>>4.
__global__ __launch_bounds__(256) void aggregate_k(const int* __restrict__ row_ptr,
                                                   const int* __restrict__ eids,
                                                   const int* __restrict__ esrc,
                                                   const float* __restrict__ ea_ws,
                                                   const float* __restrict__ xsrc,
                                                   float* __restrict__ s_ws,
                                                   float* __restrict__ out) {
    const int tid = threadIdx.x;
    const int lane = tid & 63;
    const int n = blockIdx.x * 4 + (tid >> 6);
    if (n >= N_NODES) return;
    const int h = lane >> 4;

    const int p0 = row_ptr[n];
    const int p1 = row_ptr[n + 1];

    float ax = 0.0f, ay = 0.0f, sa = 0.0f;
    for (int p = p0; p < p1; ++p) {
        const int e = eids[p];
        const int src = esrc[p];
        const float w = ea_ws[(long)e * 4 + h];
        const float2 xv = *(const float2*)(xsrc + (long)src * HC + (lane << 1));
        ax += w * xv.x;
        ay += w * xv.y;
        sa += w;
    }
    const float inv = 1.0f / (sa + 1e-8f);
    float* o = out + (long)n * HC + (lane << 1);
    o[0] = ax * inv;
    o[1] = ay * inv;
    if ((lane & 15) == 0) s_ws[(long)n * 4 + h] = sa;
}

// ---------------- edge finalize: alpha_norm = ea / (s[dst] + 1e-8) ----------------
__global__ __launch_bounds__(256) void edge_norm_k(const int* __restrict__ ei,
                                                   const int* __restrict__ flag,
                                                   const float* __restrict__ ea_ws,
                                                   const float* __restrict__ s_ws,
                                                   float* __restrict__ anorm) {
    const bool idx64 = (flag[1] != 0);
    const long i = (long)blockIdx.x * 256 + threadIdx.x;
    if (i >= (long)N_EDGES * NH) return;
    const long e = i >> 2;
    const int h = (int)(i & 3);
    const int dst = ld_dst(ei, e, idx64);
    anorm[i] = ea_ws[i] / (s_ws[(long)dst * 4 + h] + 1e-8f);
}

extern "C" void kernel_launch(void* const* d_in, const int* in_sizes, int n_in,
                              void* d_out, int out_size, void* d_ws, size_t ws_size,
                              hipStream_t stream) {
    const void* x      = d_in[0];
    const int*  ei     = (const int*)d_in[1];
    const void* eattr  = d_in[2];
    const void* dw     = d_in[3];
    const void* Wsrc   = d_in[4];
    const void* Wdst   = d_in[5];
    const void* Wedge  = d_in[6];
    const void* att    = d_in[7];
    const void* sscale = d_in[8];

    float* out   = (float*)d_out;                   // reference output dtype: float32
    float* anorm = out + (long)N_NODES * HC;
    float* araw  = anorm + (long)N_EDGES * NH;

    float* ws      = (float*)d_ws;
    int*   flag    = (int*)d_ws;                    // 64-float pad
    float* xsrc    = ws + 64;                       // N*128
    float* xdst    = xsrc + (long)N_NODES * HC;     // N*128
    float* ea      = xdst + (long)N_NODES * HC;     // E*4
    float* s_ws    = ea + (long)N_EDGES * NH;       // N*4
    int*   deg     = (int*)(s_ws + (long)N_NODES * NH);   // N
    int*   row_ptr = deg + N_NODES;                 // N+1
    int*   cursor  = row_ptr + N_NODES + 1;         // N
    int*   eids    = cursor + N_NODES;              // E
    int*   esrc    = eids + N_EDGES;                // E

    detect_k<<<1, 256, 0, stream>>>((const unsigned short*)x, ei, flag);
    zero_deg_k<<<(N_NODES + 255) / 256, 256, 0, stream>>>(deg);
    hist_k<<<(N_EDGES + 255) / 256, 256, 0, stream>>>(ei, flag, deg);
    scan_k<<<1, 256, 0, stream>>>(deg, row_ptr, cursor);
    scatter_k<<<(N_EDGES + 255) / 256, 256, 0, stream>>>(ei, flag, cursor, eids, esrc);
    node_gemm_k<<<N_NODES / 8, 256, 0, stream>>>(x, Wsrc, Wdst, flag, xsrc, xdst);
    edge_alpha_k<<<2048, 256, 0, stream>>>(ei, eattr, dw, Wedge, att, sscale,
                                           flag, xsrc, xdst, ea, araw);
    aggregate_k<<<(N_NODES + 3) / 4, 256, 0, stream>>>(row_ptr, eids, esrc, ea, xsrc, s_ws, out);
    edge_norm_k<<<((long)N_EDGES * NH + 255) / 256, 256, 0, stream>>>(ei, flag, ea, s_ws, anorm);
}

// Round 4
// 734.846 us; speedup vs baseline: 1.5451x; 1.3030x over previous
//
#include <hip/hip_runtime.h>
#include <hip/hip_bf16.h>

#define N_NODES 50000
#define N_EDGES 800000
#define IN_CH   256
#define EDGE_DIM 32
#define NH 4
#define NC 32
#define HC 128   // NH*NC
#define SCAN_BLKS 196   // 196 * 256 = 50176 >= N_NODES
#define EGROUPS (N_EDGES / 64)   // 12500 groups of 64 edges (16 per wave x 4 waves)

typedef __attribute__((ext_vector_type(8))) short bf16x8;
typedef __attribute__((ext_vector_type(4))) float f32x4;

// scan inter-block partials: device globals (keeps workspace footprint unchanged)
__device__ int g_bsum[256];
__device__ int g_boffs[256];

// hw transcendentals (avoid __exp2f/__log2f: glibc math.h name collision)
__device__ __forceinline__ float fexp2(float x) { return __builtin_amdgcn_exp2f(x); }
__device__ __forceinline__ float flog2(float x) { return __builtin_amdgcn_logf(x); }
__device__ __forceinline__ float fexp(float x)  { return __builtin_amdgcn_exp2f(x * 1.44269504089f); }

// fast tanh: 1 - 2/(e^{2x}+1); exact saturation at +/-inf, ~1e-7 abs err
__device__ __forceinline__ float ftanh(float x) {
    const float e = fexp2(x * 2.88539008178f);   // 2*log2(e)
    return 1.0f - 2.0f * __builtin_amdgcn_rcpf(e + 1.0f);
}

// f32 -> bf16 RNE
__device__ __forceinline__ unsigned short f2bf(float f) {
    union { float f; unsigned int u; } v; v.f = f;
    const unsigned int r = v.u + 0x7fffu + ((v.u >> 16) & 1u);
    return (unsigned short)(r >> 16);
}

// Dual-dtype scalar load: f32 flag selects fp32 vs bf16 interpretation of the raw buffer.
__device__ __forceinline__ float ldf(const void* p, long i, bool f32) {
    return f32 ? ((const float*)p)[i]
               : __bfloat162float(((const __hip_bfloat16*)p)[i]);
}

// Dual-width index loads: idx64 => buffer is int64 [2,E] (values < 2^31, read low words).
__device__ __forceinline__ int ld_src(const int* ei, long e, bool idx64) {
    return idx64 ? ei[2 * e] : ei[e];
}
__device__ __forceinline__ int ld_dst(const int* ei, long e, bool idx64) {
    return idx64 ? ei[2 * ((long)N_EDGES + e)] : ei[(long)N_EDGES + e];
}

// ---------------- dtype detection (runs every call, deterministic) ----------------
__global__ __launch_bounds__(256) void detect_k(const unsigned short* __restrict__ xu,
                                                const int* __restrict__ ei,
                                                int* __restrict__ flag) {
    __shared__ int zc, bc, nz_idx;
    if (threadIdx.x == 0) { zc = 0; bc = 0; nz_idx = 0; }
    __syncthreads();
    int z = 0, b = 0, hi = 0;
    for (int i = threadIdx.x; i < 16384; i += 256) {
        const unsigned short w = xu[2 * i];
        if (w == 0) ++z;
        if ((w & 0x7F80) == 0x7F80) ++b;
    }
    for (int i = threadIdx.x; i < 8192; i += 256)
        if (ei[2 * i + 1] != 0) hi = 1;
    atomicAdd(&zc, z);
    atomicAdd(&bc, b);
    if (hi) atomicAdd(&nz_idx, 1);
    __syncthreads();
    if (threadIdx.x == 0) {
        flag[0] = (zc > 8192 || bc > 0) ? 1 : 0;  // 1 => fp32 float buffers
        flag[1] = (nz_idx == 0) ? 1 : 0;          // 1 => int64 indices
    }
}

// ---------------- CSR build ----------------
__global__ __launch_bounds__(256) void zero_deg_k(int* __restrict__ deg) {
    const int i = blockIdx.x * 256 + threadIdx.x;
    if (i < N_NODES) deg[i] = 0;
}

__global__ __launch_bounds__(256) void hist_k(const int* __restrict__ ei,
                                              const int* __restrict__ flag,
                                              int* __restrict__ deg) {
    const bool idx64 = (flag[1] != 0);
    const long e = (long)blockIdx.x * 256 + threadIdx.x;
    if (e < N_EDGES) atomicAdd(&deg[ld_dst(ei, e, idx64)], 1);
}

// ---- 3-phase parallel exclusive scan (replaces the single-block serial scan) ----
__global__ __launch_bounds__(256) void scan1_k(const int* __restrict__ deg,
                                               int* __restrict__ row_ptr) {
    __shared__ int wsum[4];
    const int tid = threadIdx.x;
    const int lane = tid & 63, wid = tid >> 6;
    const int i = blockIdx.x * 256 + tid;
    const int v = (i < N_NODES) ? deg[i] : 0;
    int x = v;
    #pragma unroll
    for (int off = 1; off < 64; off <<= 1) {
        const int t = __shfl_up(x, off);
        if (lane >= off) x += t;
    }
    if (lane == 63) wsum[wid] = x;
    __syncthreads();
    int wpre = 0;
    for (int w = 0; w < wid; ++w) wpre += wsum[w];
    if (i < N_NODES) row_ptr[i] = wpre + x - v;          // block-local exclusive
    if (tid == 0) g_bsum[blockIdx.x] = wsum[0] + wsum[1] + wsum[2] + wsum[3];
}

__global__ __launch_bounds__(256) void scan2_k(int* __restrict__ row_ptr) {
    __shared__ int wsum[4];
    const int tid = threadIdx.x;
    const int lane = tid & 63, wid = tid >> 6;
    const int v = (tid < SCAN_BLKS) ? g_bsum[tid] : 0;
    int x = v;
    #pragma unroll
    for (int off = 1; off < 64; off <<= 1) {
        const int t = __shfl_up(x, off);
        if (lane >= off) x += t;
    }
    if (lane == 63) wsum[wid] = x;
    __syncthreads();
    int wpre = 0;
    for (int w = 0; w < wid; ++w) wpre += wsum[w];
    if (tid < SCAN_BLKS) g_boffs[tid] = wpre + x - v;
    if (tid == 0) row_ptr[N_NODES] = N_EDGES;            // total degree is constant
}

__global__ __launch_bounds__(256) void scan3_k(int* __restrict__ row_ptr,
                                               int* __restrict__ cursor) {
    const int i = blockIdx.x * 256 + threadIdx.x;
    if (i < N_NODES) {
        const int t = row_ptr[i] + g_boffs[blockIdx.x];
        row_ptr[i] = t;
        cursor[i] = t;
    }
}

__global__ __launch_bounds__(256) void scatter_k(const int* __restrict__ ei,
                                                 const int* __restrict__ flag,
                                                 int* __restrict__ cursor,
                                                 int* __restrict__ eids,
                                                 int* __restrict__ esrc) {
    const bool idx64 = (flag[1] != 0);
    const long e = (long)blockIdx.x * 256 + threadIdx.x;
    if (e >= N_EDGES) return;
    const int dst = ld_dst(ei, e, idx64);
    const int src = ld_src(ei, e, idx64);
    const int pos = atomicAdd(&cursor[dst], 1);
    eids[pos] = (int)e;
    esrc[pos] = src;
}

// ---------------- node GEMMs: x_src = x@W_src, x_dst = x@W_dst ----------------
__global__ __launch_bounds__(256) void node_gemm_k(const void* __restrict__ x,
                                                   const void* __restrict__ Wsrc,
                                                   const void* __restrict__ Wdst,
                                                   const int* __restrict__ flag,
                                                   float* __restrict__ xsrc,
                                                   float* __restrict__ xdst) {
    const bool f32 = (flag[0] != 0);
    __shared__ float sx[8][IN_CH];
    const int tid = threadIdx.x;
    const long n0 = (long)blockIdx.x * 8;
    #pragma unroll
    for (int r = 0; r < 8; ++r)
        sx[r][tid] = ldf(x, (n0 + r) * IN_CH + tid, f32);
    __syncthreads();

    const int mat = tid >> 7;
    const int col = tid & 127;
    const void* __restrict__ W = mat ? Wdst : Wsrc;
    float acc[8] = {0,0,0,0,0,0,0,0};
    for (int k = 0; k < IN_CH; k += 4) {
        const float w0 = ldf(W, (long)(k + 0) * HC + col, f32);
        const float w1 = ldf(W, (long)(k + 1) * HC + col, f32);
        const float w2 = ldf(W, (long)(k + 2) * HC + col, f32);
        const float w3 = ldf(W, (long)(k + 3) * HC + col, f32);
        #pragma unroll
        for (int r = 0; r < 8; ++r) {
            const float4 sv = *(const float4*)&sx[r][k];
            acc[r] += sv.x * w0 + sv.y * w1 + sv.z * w2 + sv.w * w3;
        }
    }
    float* __restrict__ o = mat ? xdst : xsrc;
    #pragma unroll
    for (int r = 0; r < 8; ++r)
        o[(n0 + r) * HC + col] = acc[r];
}

// ---------------- edge alpha pass: MFMA-fused, 16 edges per wave ----------------
// mfma_f32_16x16x32_bf16: M=16 edges, N=16 cols (x8 tiles = 128), K=32 = EDGE_DIM.
// A-frag: lane l holds eattr[e0 + (l&15)][8*(l>>4) + i]  (8 contiguous bf16 = 16B load)
// B-frag: lane l holds W_edge[8*(l>>4) + i][16t + (l&15)] (registers, loaded once)
// C/D   : lane l holds ef[e0 + 4*(l>>4) + r][16t + (l&15)] (HW-verified layout)
__global__ __launch_bounds__(256) void edge_alpha_k(const int* __restrict__ ei,
                                                    const void* __restrict__ eattr,
                                                    const void* __restrict__ dw,
                                                    const void* __restrict__ Wedge,
                                                    const void* __restrict__ att,
                                                    const void* __restrict__ sscale,
                                                    const int* __restrict__ flag,
                                                    const float* __restrict__ xsrc,
                                                    const float* __restrict__ xdst,
                                                    float* __restrict__ ea_ws,
                                                    float* __restrict__ araw_out) {
    const bool f32   = (flag[0] != 0);
    const bool idx64 = (flag[1] != 0);
    __shared__ int   sSrc[4][16];
    __shared__ int   sDst[4][16];
    __shared__ float sDw[4][16];

    const int tid = threadIdx.x;
    const int l   = tid & 63;
    const int wid = tid >> 6;
    const int jj  = l & 15;     // col-within-tile / edge-row for A
    const int hi  = l >> 4;     // lane quarter-group

    // B fragments: W_edge[32][128] columns, loaded once per (persistent) block.
    bf16x8 bfrag[8];
    #pragma unroll
    for (int t = 0; t < 8; ++t) {
        union { unsigned short u[8]; bf16x8 v; } bu;
        #pragma unroll
        for (int i = 0; i < 8; ++i) {
            const int k = hi * 8 + i;
            const int col = t * 16 + jj;
            if (f32) bu.u[i] = f2bf(((const float*)Wedge)[k * HC + col]);
            else     bu.u[i] = ((const unsigned short*)Wedge)[k * HC + col];
        }
        bfrag[t] = bu.v;
    }
    float attv[8];
    #pragma unroll
    for (int t = 0; t < 8; ++t) attv[t] = ldf(att, t * 16 + jj, f32);
    const float ssv = ldf(sscale, l & 3, f32);

    for (long g = blockIdx.x; g < EGROUPS; g += (long)gridDim.x) {
        const long e0 = g * 64 + (long)wid * 16;

        // stage per-edge scalars (16 edges) into wave-private LDS
        if (l < 16)      sSrc[wid][l]      = ld_src(ei, e0 + l, idx64);
        else if (l < 32) sDst[wid][l - 16] = ld_dst(ei, e0 + (l - 16), idx64);
        else if (l < 48) sDw[wid][l - 32]  = ldf(dw, e0 + (l - 32), f32);
        __builtin_amdgcn_wave_barrier();

        // A fragment: 8 contiguous k-values of edge (e0 + jj)
        bf16x8 afrag;
        if (f32) {
            const float* ar = (const float*)eattr + (e0 + jj) * EDGE_DIM + hi * 8;
            const float4 p0 = *(const float4*)ar;
            const float4 p1 = *(const float4*)(ar + 4);
            union { unsigned short u[8]; bf16x8 v; } au;
            au.u[0] = f2bf(p0.x); au.u[1] = f2bf(p0.y); au.u[2] = f2bf(p0.z); au.u[3] = f2bf(p0.w);
            au.u[4] = f2bf(p1.x); au.u[5] = f2bf(p1.y); au.u[6] = f2bf(p1.z); au.u[7] = f2bf(p1.w);
            afrag = au.v;
        } else {
            afrag = *(const bf16x8*)((const unsigned short*)eattr + (e0 + jj) * EDGE_DIM + hi * 8);
        }

        // e_feat[16 edges][128 cols] via 8 MFMAs (K=32 in one shot each)
        const f32x4 zero = {0.f, 0.f, 0.f, 0.f};
        f32x4 acc[8];
        #pragma unroll
        for (int t = 0; t < 8; ++t)
            acc[t] = __builtin_amdgcn_mfma_f32_16x16x32_bf16(afrag, bfrag[t], zero, 0, 0, 0);

        // tanh + att-weighted per-head partial sums
        float hsum[4][4] = {{0,0,0,0},{0,0,0,0},{0,0,0,0},{0,0,0,0}};
        #pragma unroll
        for (int r = 0; r < 4; ++r) {
            const int sI = sSrc[wid][hi * 4 + r];   // LDS broadcast within group
            const int dI = sDst[wid][hi * 4 + r];
            const float* bs = xsrc + (long)sI * HC + jj;
            const float* bd = xdst + (long)dI * HC + jj;
            float xsv[8], xdv[8];
            #pragma unroll
            for (int t = 0; t < 8; ++t) xsv[t] = bs[t * 16];
            #pragma unroll
            for (int t = 0; t < 8; ++t) xdv[t] = bd[t * 16];
            #pragma unroll
            for (int t = 0; t < 8; ++t) {
                const float v = ftanh(acc[t][r] + xsv[t] + xdv[t]) * attv[t];
                hsum[r][t >> 1] += v;
            }
        }

        // reduce each (edge r, head h) over the 16 lanes of the group
        #pragma unroll
        for (int r = 0; r < 4; ++r)
            #pragma unroll
            for (int h2 = 0; h2 < 4; ++h2) {
                float v = hsum[r][h2];
                v += __shfl_xor(v, 1);
                v += __shfl_xor(v, 2);
                v += __shfl_xor(v, 4);
                v += __shfl_xor(v, 8);
                hsum[r][h2] = v;
            }

        // lane jj handles (edge r_sel = jj>>2, head hh = jj&3): coalesced 256B stores
        float val = hsum[0][0];
        #pragma unroll
        for (int r = 0; r < 4; ++r)
            #pragma unroll
            for (int h2 = 0; h2 < 4; ++h2)
                if (jj == r * 4 + h2) val = hsum[r][h2];

        const int r_sel = jj >> 2;
        const long er = e0 + hi * 4 + r_sel;
        const float dwv = sDw[wid][hi * 4 + r_sel];
        araw_out[er * 4 + (jj & 3)] = val;                    // pre-decay logit
        const float d = fexp2(ssv * flog2(dwv));              // dwv ** ss
        ea_ws[er * 4 + (jj & 3)] = fexp(val * d);
        __builtin_amdgcn_wave_barrier();
    }
}

// ---------------- CSR aggregation: one wave per dst node, no atomics ----------------
// lane owns channels {2*lane, 2*lane+1}; head h = lane>>4.
__global__ __launch_bounds__(256) void aggregate_k(const int* __restrict__ row_ptr,
                                                   const int* __restrict__ eids,
                                                   const int* __restrict__ esrc,
                                                   const float* __restrict__ ea_ws,
                                                   const float* __restrict__ xsrc,
                                                   float* __restrict__ s_ws,
                                                   float* __restrict__ out) {
    const int tid = threadIdx.x;
    const int lane = tid & 63;
    const int n = blockIdx.x * 4 + (tid >> 6);
    if (n >= N_NODES) return;
    const int h = lane >> 4;

    const int p0 = row_ptr[n];
    const int p1 = row_ptr[n + 1];

    float ax = 0.0f, ay = 0.0f, sa = 0.0f;
    for (int p = p0; p < p1; ++p) {
        const int e = eids[p];
        const int src = esrc[p];
        const float w = ea_ws[(long)e * 4 + h];
        const float2 xv = *(const float2*)(xsrc + (long)src * HC + (lane << 1));
        ax += w * xv.x;
        ay += w * xv.y;
        sa += w;
    }
    const float inv = 1.0f / (sa + 1e-8f);
    float* o = out + (long)n * HC + (lane << 1);
    o[0] = ax * inv;
    o[1] = ay * inv;
    if ((lane & 15) == 0) s_ws[(long)n * 4 + h] = sa;
}

// ---------------- edge finalize: alpha_norm = ea / (s[dst] + 1e-8) ----------------
__global__ __launch_bounds__(256) void edge_norm_k(const int* __restrict__ ei,
                                                   const int* __restrict__ flag,
                                                   const float* __restrict__ ea_ws,
                                                   const float* __restrict__ s_ws,
                                                   float* __restrict__ anorm) {
    const bool idx64 = (flag[1] != 0);
    const long i = (long)blockIdx.x * 256 + threadIdx.x;
    if (i >= (long)N_EDGES * NH) return;
    const long e = i >> 2;
    const int h = (int)(i & 3);
    const int dst = ld_dst(ei, e, idx64);
    anorm[i] = ea_ws[i] / (s_ws[(long)dst * 4 + h] + 1e-8f);
}

extern "C" void kernel_launch(void* const* d_in, const int* in_sizes, int n_in,
                              void* d_out, int out_size, void* d_ws, size_t ws_size,
                              hipStream_t stream) {
    const void* x      = d_in[0];
    const int*  ei     = (const int*)d_in[1];
    const void* eattr  = d_in[2];
    const void* dw     = d_in[3];
    const void* Wsrc   = d_in[4];
    const void* Wdst   = d_in[5];
    const void* Wedge  = d_in[6];
    const void* att    = d_in[7];
    const void* sscale = d_in[8];

    float* out   = (float*)d_out;                   // reference output dtype: float32
    float* anorm = out + (long)N_NODES * HC;
    float* araw  = anorm + (long)N_EDGES * NH;

    float* ws      = (float*)d_ws;
    int*   flag    = (int*)d_ws;                    // 64-float pad
    float* xsrc    = ws + 64;                       // N*128
    float* xdst    = xsrc + (long)N_NODES * HC;     // N*128
    float* ea      = xdst + (long)N_NODES * HC;     // E*4
    float* s_ws    = ea + (long)N_EDGES * NH;       // N*4
    int*   deg     = (int*)(s_ws + (long)N_NODES * NH);   // N
    int*   row_ptr = deg + N_NODES;                 // N+1
    int*   cursor  = row_ptr + N_NODES + 1;         // N
    int*   eids    = cursor + N_NODES;              // E
    int*   esrc    = eids + N_EDGES;                // E

    detect_k<<<1, 256, 0, stream>>>((const unsigned short*)x, ei, flag);
    zero_deg_k<<<(N_NODES + 255) / 256, 256, 0, stream>>>(deg);
    hist_k<<<(N_EDGES + 255) / 256, 256, 0, stream>>>(ei, flag, deg);
    scan1_k<<<SCAN_BLKS, 256, 0, stream>>>(deg, row_ptr);
    scan2_k<<<1, 256, 0, stream>>>(row_ptr);
    scan3_k<<<SCAN_BLKS, 256, 0, stream>>>(row_ptr, cursor);
    scatter_k<<<(N_EDGES + 255) / 256, 256, 0, stream>>>(ei, flag, cursor, eids, esrc);
    node_gemm_k<<<N_NODES / 8, 256, 0, stream>>>(x, Wsrc, Wdst, flag, xsrc, xdst);
    edge_alpha_k<<<2048, 256, 0, stream>>>(ei, eattr, dw, Wedge, att, sscale,
                                           flag, xsrc, xdst, ea, araw);
    aggregate_k<<<(N_NODES + 3) / 4, 256, 0, stream>>>(row_ptr, eids, esrc, ea, xsrc, s_ws, out);
    edge_norm_k<<<((long)N_EDGES * NH + 255) / 256, 256, 0, stream>>>(ei, flag, ea, s_ws, anorm);
}

// Round 5
// 729.667 us; speedup vs baseline: 1.5561x; 1.0071x over previous
//
#include <hip/hip_runtime.h>
#include <hip/hip_bf16.h>

#define N_NODES 50000
#define N_EDGES 800000
#define IN_CH   256
#define EDGE_DIM 32
#define NH 4
#define NC 32
#define HC 128   // NH*NC
#define SCAN_BLKS 196   // 196 * 256 = 50176 >= N_NODES
#define EGROUPS (N_EDGES / 64)   // 12500 groups of 64 edges (16 per wave x 4 waves)
#define NTILES (N_NODES / 16)    // 3125 16-node tiles (exact)

typedef __attribute__((ext_vector_type(8))) short bf16x8;
typedef __attribute__((ext_vector_type(4))) float f32x4;

// scan inter-block partials: device globals (keeps workspace footprint unchanged)
__device__ int g_bsum[256];
__device__ int g_boffs[256];

// hw transcendentals (avoid __exp2f/__log2f: glibc math.h name collision)
__device__ __forceinline__ float fexp2(float x) { return __builtin_amdgcn_exp2f(x); }
__device__ __forceinline__ float flog2(float x) { return __builtin_amdgcn_logf(x); }
__device__ __forceinline__ float fexp(float x)  { return __builtin_amdgcn_exp2f(x * 1.44269504089f); }

// fast tanh: 1 - 2/(e^{2x}+1); exact saturation at +/-inf, ~1e-7 abs err
__device__ __forceinline__ float ftanh(float x) {
    const float e = fexp2(x * 2.88539008178f);   // 2*log2(e)
    return 1.0f - 2.0f * __builtin_amdgcn_rcpf(e + 1.0f);
}

// f32 -> bf16 RNE
__device__ __forceinline__ unsigned short f2bf(float f) {
    union { float f; unsigned int u; } v; v.f = f;
    const unsigned int r = v.u + 0x7fffu + ((v.u >> 16) & 1u);
    return (unsigned short)(r >> 16);
}

// Dual-dtype scalar load: f32 flag selects fp32 vs bf16 interpretation of the raw buffer.
__device__ __forceinline__ float ldf(const void* p, long i, bool f32) {
    return f32 ? ((const float*)p)[i]
               : __bfloat162float(((const __hip_bfloat16*)p)[i]);
}

// Dual-width index loads: idx64 => buffer is int64 [2,E] (values < 2^31, read low words).
__device__ __forceinline__ int ld_src(const int* ei, long e, bool idx64) {
    return idx64 ? ei[2 * e] : ei[e];
}
__device__ __forceinline__ int ld_dst(const int* ei, long e, bool idx64) {
    return idx64 ? ei[2 * ((long)N_EDGES + e)] : ei[(long)N_EDGES + e];
}

// ---------------- dtype detection (runs every call, deterministic) ----------------
__global__ __launch_bounds__(256) void detect_k(const unsigned short* __restrict__ xu,
                                                const int* __restrict__ ei,
                                                int* __restrict__ flag) {
    __shared__ int zc, bc, nz_idx;
    if (threadIdx.x == 0) { zc = 0; bc = 0; nz_idx = 0; }
    __syncthreads();
    int z = 0, b = 0, hi = 0;
    for (int i = threadIdx.x; i < 16384; i += 256) {
        const unsigned short w = xu[2 * i];
        if (w == 0) ++z;
        if ((w & 0x7F80) == 0x7F80) ++b;
    }
    for (int i = threadIdx.x; i < 8192; i += 256)
        if (ei[2 * i + 1] != 0) hi = 1;
    atomicAdd(&zc, z);
    atomicAdd(&bc, b);
    if (hi) atomicAdd(&nz_idx, 1);
    __syncthreads();
    if (threadIdx.x == 0) {
        flag[0] = (zc > 8192 || bc > 0) ? 1 : 0;  // 1 => fp32 float buffers
        flag[1] = (nz_idx == 0) ? 1 : 0;          // 1 => int64 indices
    }
}

// ---------------- CSR build ----------------
__global__ __launch_bounds__(256) void zero_deg_k(int* __restrict__ deg) {
    const int i = blockIdx.x * 256 + threadIdx.x;
    if (i < N_NODES) deg[i] = 0;
}

__global__ __launch_bounds__(256) void hist_k(const int* __restrict__ ei,
                                              const int* __restrict__ flag,
                                              int* __restrict__ deg) {
    const bool idx64 = (flag[1] != 0);
    const long e = (long)blockIdx.x * 256 + threadIdx.x;
    if (e < N_EDGES) atomicAdd(&deg[ld_dst(ei, e, idx64)], 1);
}

// ---- 3-phase parallel exclusive scan ----
__global__ __launch_bounds__(256) void scan1_k(const int* __restrict__ deg,
                                               int* __restrict__ row_ptr) {
    __shared__ int wsum[4];
    const int tid = threadIdx.x;
    const int lane = tid & 63, wid = tid >> 6;
    const int i = blockIdx.x * 256 + tid;
    const int v = (i < N_NODES) ? deg[i] : 0;
    int x = v;
    #pragma unroll
    for (int off = 1; off < 64; off <<= 1) {
        const int t = __shfl_up(x, off);
        if (lane >= off) x += t;
    }
    if (lane == 63) wsum[wid] = x;
    __syncthreads();
    int wpre = 0;
    for (int w = 0; w < wid; ++w) wpre += wsum[w];
    if (i < N_NODES) row_ptr[i] = wpre + x - v;          // block-local exclusive
    if (tid == 0) g_bsum[blockIdx.x] = wsum[0] + wsum[1] + wsum[2] + wsum[3];
}

__global__ __launch_bounds__(256) void scan2_k(int* __restrict__ row_ptr) {
    __shared__ int wsum[4];
    const int tid = threadIdx.x;
    const int lane = tid & 63, wid = tid >> 6;
    const int v = (tid < SCAN_BLKS) ? g_bsum[tid] : 0;
    int x = v;
    #pragma unroll
    for (int off = 1; off < 64; off <<= 1) {
        const int t = __shfl_up(x, off);
        if (lane >= off) x += t;
    }
    if (lane == 63) wsum[wid] = x;
    __syncthreads();
    int wpre = 0;
    for (int w = 0; w < wid; ++w) wpre += wsum[w];
    if (tid < SCAN_BLKS) g_boffs[tid] = wpre + x - v;
    if (tid == 0) row_ptr[N_NODES] = N_EDGES;            // total degree is constant
}

__global__ __launch_bounds__(256) void scan3_k(int* __restrict__ row_ptr,
                                               int* __restrict__ cursor) {
    const int i = blockIdx.x * 256 + threadIdx.x;
    if (i < N_NODES) {
        const int t = row_ptr[i] + g_boffs[blockIdx.x];
        row_ptr[i] = t;
        cursor[i] = t;
    }
}

__global__ __launch_bounds__(256) void scatter_k(const int* __restrict__ ei,
                                                 const int* __restrict__ flag,
                                                 int* __restrict__ cursor,
                                                 int* __restrict__ eids,
                                                 int* __restrict__ esrc) {
    const bool idx64 = (flag[1] != 0);
    const long e = (long)blockIdx.x * 256 + threadIdx.x;
    if (e >= N_EDGES) return;
    const int dst = ld_dst(ei, e, idx64);
    const int src = ld_src(ei, e, idx64);
    const int pos = atomicAdd(&cursor[dst], 1);
    eids[pos] = (int)e;
    esrc[pos] = src;
}

// ---------------- node GEMMs (bf16 fast path): MFMA, 16 nodes per wave-tile ----------------
// Same validated fragment mapping as edge_alpha_k:
//   A: lane l holds x[n0 + (l&15)][ks*32 + 8*(l>>4) + i]
//   B: lane l holds Wcat[ks*32 + 8*(l>>4) + i][cbase + t*16 + (l&15)]
//   C: lane l holds out[n0 + 4*(l>>4) + r][cbase + t*16 + (l&15)]
// Wave w covers cols [w*64, w*64+64) of the 256-wide concat [Wsrc | Wdst].
// B = 32 bf16x8 = 128 VGPR/lane, loaded once per persistent block.
__global__ __launch_bounds__(256) void node_gemm_mfma_k(const unsigned short* __restrict__ x,
                                                        const unsigned short* __restrict__ Wsrc,
                                                        const unsigned short* __restrict__ Wdst,
                                                        const int* __restrict__ flag,
                                                        float* __restrict__ xsrc,
                                                        float* __restrict__ xdst) {
    if (flag[0] != 0) return;        // fp32 inputs: node_gemm_f32_k handles it
    const int tid = threadIdx.x;
    const int l   = tid & 63;
    const int w   = tid >> 6;
    const int jj  = l & 15;
    const int hi  = l >> 4;
    const int cbase = w * 64;

    bf16x8 bfrag[8][4];
    #pragma unroll
    for (int ks = 0; ks < 8; ++ks)
        #pragma unroll
        for (int t = 0; t < 4; ++t) {
            const int c = cbase + t * 16 + jj;
            const unsigned short* Wp = (c < HC) ? (Wsrc + c) : (Wdst + (c - HC));
            union { unsigned short u[8]; bf16x8 v; } bu;
            #pragma unroll
            for (int i = 0; i < 8; ++i)
                bu.u[i] = Wp[(ks * 32 + hi * 8 + i) * HC];
            bfrag[ks][t] = bu.v;
        }

    for (int nt = blockIdx.x; nt < NTILES; nt += gridDim.x) {
        const long n0 = (long)nt * 16;
        const unsigned short* xr = x + (n0 + jj) * IN_CH + hi * 8;
        bf16x8 afrag[8];
        #pragma unroll
        for (int ks = 0; ks < 8; ++ks)
            afrag[ks] = *(const bf16x8*)(xr + ks * 32);

        f32x4 acc[4];
        #pragma unroll
        for (int t = 0; t < 4; ++t) acc[t] = (f32x4){0.f, 0.f, 0.f, 0.f};
        #pragma unroll
        for (int ks = 0; ks < 8; ++ks)
            #pragma unroll
            for (int t = 0; t < 4; ++t)
                acc[t] = __builtin_amdgcn_mfma_f32_16x16x32_bf16(afrag[ks], bfrag[ks][t], acc[t], 0, 0, 0);

        #pragma unroll
        for (int t = 0; t < 4; ++t) {
            const int c = cbase + t * 16 + jj;
            float* obase = (c < HC) ? (xsrc + c) : (xdst + (c - HC));
            #pragma unroll
            for (int r = 0; r < 4; ++r)
                obase[(n0 + hi * 4 + r) * HC] = acc[t][r];
        }
    }
}

// ---------------- node GEMMs (fp32 fallback): VALU path ----------------
__global__ __launch_bounds__(256) void node_gemm_f32_k(const void* __restrict__ x,
                                                       const void* __restrict__ Wsrc,
                                                       const void* __restrict__ Wdst,
                                                       const int* __restrict__ flag,
                                                       float* __restrict__ xsrc,
                                                       float* __restrict__ xdst) {
    if (flag[0] == 0) return;        // bf16 inputs: MFMA kernel handles it
    __shared__ float sx[8][IN_CH];
    const int tid = threadIdx.x;
    const long n0 = (long)blockIdx.x * 8;
    #pragma unroll
    for (int r = 0; r < 8; ++r)
        sx[r][tid] = ((const float*)x)[(n0 + r) * IN_CH + tid];
    __syncthreads();

    const int mat = tid >> 7;
    const int col = tid & 127;
    const float* __restrict__ W = (const float*)(mat ? Wdst : Wsrc);
    float acc[8] = {0,0,0,0,0,0,0,0};
    for (int k = 0; k < IN_CH; k += 4) {
        const float w0 = W[(long)(k + 0) * HC + col];
        const float w1 = W[(long)(k + 1) * HC + col];
        const float w2 = W[(long)(k + 2) * HC + col];
        const float w3 = W[(long)(k + 3) * HC + col];
        #pragma unroll
        for (int r = 0; r < 8; ++r) {
            const float4 sv = *(const float4*)&sx[r][k];
            acc[r] += sv.x * w0 + sv.y * w1 + sv.z * w2 + sv.w * w3;
        }
    }
    float* __restrict__ o = mat ? xdst : xsrc;
    #pragma unroll
    for (int r = 0; r < 8; ++r)
        o[(n0 + r) * HC + col] = acc[r];
}

// ---------------- edge alpha pass: MFMA-fused, 16 edges per wave ----------------
// mfma_f32_16x16x32_bf16: M=16 edges, N=16 cols (x8 tiles = 128), K=32 = EDGE_DIM.
__global__ __launch_bounds__(256) void edge_alpha_k(const int* __restrict__ ei,
                                                    const void* __restrict__ eattr,
                                                    const void* __restrict__ dw,
                                                    const void* __restrict__ Wedge,
                                                    const void* __restrict__ att,
                                                    const void* __restrict__ sscale,
                                                    const int* __restrict__ flag,
                                                    const float* __restrict__ xsrc,
                                                    const float* __restrict__ xdst,
                                                    float* __restrict__ ea_ws,
                                                    float* __restrict__ araw_out) {
    const bool f32   = (flag[0] != 0);
    const bool idx64 = (flag[1] != 0);
    __shared__ int   sSrc[4][16];
    __shared__ int   sDst[4][16];
    __shared__ float sDw[4][16];

    const int tid = threadIdx.x;
    const int l   = tid & 63;
    const int wid = tid >> 6;
    const int jj  = l & 15;     // col-within-tile / edge-row for A
    const int hi  = l >> 4;     // lane quarter-group

    // B fragments: W_edge[32][128] columns, loaded once per (persistent) block.
    bf16x8 bfrag[8];
    #pragma unroll
    for (int t = 0; t < 8; ++t) {
        union { unsigned short u[8]; bf16x8 v; } bu;
        #pragma unroll
        for (int i = 0; i < 8; ++i) {
            const int k = hi * 8 + i;
            const int col = t * 16 + jj;
            if (f32) bu.u[i] = f2bf(((const float*)Wedge)[k * HC + col]);
            else     bu.u[i] = ((const unsigned short*)Wedge)[k * HC + col];
        }
        bfrag[t] = bu.v;
    }
    float attv[8];
    #pragma unroll
    for (int t = 0; t < 8; ++t) attv[t] = ldf(att, t * 16 + jj, f32);
    const float ssv = ldf(sscale, l & 3, f32);

    for (long g = blockIdx.x; g < EGROUPS; g += (long)gridDim.x) {
        const long e0 = g * 64 + (long)wid * 16;

        // stage per-edge scalars (16 edges) into wave-private LDS
        if (l < 16)      sSrc[wid][l]      = ld_src(ei, e0 + l, idx64);
        else if (l < 32) sDst[wid][l - 16] = ld_dst(ei, e0 + (l - 16), idx64);
        else if (l < 48) sDw[wid][l - 32]  = ldf(dw, e0 + (l - 32), f32);
        __builtin_amdgcn_wave_barrier();

        // A fragment: 8 contiguous k-values of edge (e0 + jj)
        bf16x8 afrag;
        if (f32) {
            const float* ar = (const float*)eattr + (e0 + jj) * EDGE_DIM + hi * 8;
            const float4 p0 = *(const float4*)ar;
            const float4 p1 = *(const float4*)(ar + 4);
            union { unsigned short u[8]; bf16x8 v; } au;
            au.u[0] = f2bf(p0.x); au.u[1] = f2bf(p0.y); au.u[2] = f2bf(p0.z); au.u[3] = f2bf(p0.w);
            au.u[4] = f2bf(p1.x); au.u[5] = f2bf(p1.y); au.u[6] = f2bf(p1.z); au.u[7] = f2bf(p1.w);
            afrag = au.v;
        } else {
            afrag = *(const bf16x8*)((const unsigned short*)eattr + (e0 + jj) * EDGE_DIM + hi * 8);
        }

        // e_feat[16 edges][128 cols] via 8 MFMAs (K=32 in one shot each)
        const f32x4 zero = {0.f, 0.f, 0.f, 0.f};
        f32x4 acc[8];
        #pragma unroll
        for (int t = 0; t < 8; ++t)
            acc[t] = __builtin_amdgcn_mfma_f32_16x16x32_bf16(afrag, bfrag[t], zero, 0, 0, 0);

        // tanh + att-weighted per-head partial sums
        float hsum[4][4] = {{0,0,0,0},{0,0,0,0},{0,0,0,0},{0,0,0,0}};
        #pragma unroll
        for (int r = 0; r < 4; ++r) {
            const int sI = sSrc[wid][hi * 4 + r];   // LDS broadcast within group
            const int dI = sDst[wid][hi * 4 + r];
            const float* bs = xsrc + (long)sI * HC + jj;
            const float* bd = xdst + (long)dI * HC + jj;
            float xsv[8], xdv[8];
            #pragma unroll
            for (int t = 0; t < 8; ++t) xsv[t] = bs[t * 16];
            #pragma unroll
            for (int t = 0; t < 8; ++t) xdv[t] = bd[t * 16];
            #pragma unroll
            for (int t = 0; t < 8; ++t) {
                const float v = ftanh(acc[t][r] + xsv[t] + xdv[t]) * attv[t];
                hsum[r][t >> 1] += v;
            }
        }

        // reduce each (edge r, head h) over the 16 lanes of the group
        #pragma unroll
        for (int r = 0; r < 4; ++r)
            #pragma unroll
            for (int h2 = 0; h2 < 4; ++h2) {
                float v = hsum[r][h2];
                v += __shfl_xor(v, 1);
                v += __shfl_xor(v, 2);
                v += __shfl_xor(v, 4);
                v += __shfl_xor(v, 8);
                hsum[r][h2] = v;
            }

        // lane jj handles (edge r_sel = jj>>2, head hh = jj&3): coalesced 256B stores
        float val = hsum[0][0];
        #pragma unroll
        for (int r = 0; r < 4; ++r)
            #pragma unroll
            for (int h2 = 0; h2 < 4; ++h2)
                if (jj == r * 4 + h2) val = hsum[r][h2];

        const int r_sel = jj >> 2;
        const long er = e0 + hi * 4 + r_sel;
        const float dwv = sDw[wid][hi * 4 + r_sel];
        araw_out[er * 4 + (jj & 3)] = val;                    // pre-decay logit
        const float d = fexp2(ssv * flog2(dwv));              // dwv ** ss
        ea_ws[er * 4 + (jj & 3)] = fexp(val * d);
        __builtin_amdgcn_wave_barrier();
    }
}

// ---------------- CSR aggregation: one wave per dst node, no atomics ----------------
// lane owns channels {2*lane, 2*lane+1}; head h = lane>>4.
__global__ __launch_bounds__(256) void aggregate_k(const int* __restrict__ row_ptr,
                                                   const int* __restrict__ eids,
                                                   const int* __restrict__ esrc,
                                                   const float* __restrict__ ea_ws,
                                                   const float* __restrict__ xsrc,
                                                   float* __restrict__ s_ws,
                                                   float* __restrict__ out) {
    const int tid = threadIdx.x;
    const int lane = tid & 63;
    const int n = blockIdx.x * 4 + (tid >> 6);
    if (n >= N_NODES) return;
    const int h = lane >> 4;

    const int p0 = row_ptr[n];
    const int p1 = row_ptr[n + 1];

    float ax = 0.0f, ay = 0.0f, sa = 0.0f;
    for (int p = p0; p < p1; ++p) {
        const int e = eids[p];
        const int src = esrc[p];
        const float w = ea_ws[(long)e * 4 + h];
        const float2 xv = *(const float2*)(xsrc + (long)src * HC + (lane << 1));
        ax += w * xv.x;
        ay += w * xv.y;
        sa += w;
    }
    const float inv = 1.0f / (sa + 1e-8f);
    float* o = out + (long)n * HC + (lane << 1);
    o[0] = ax * inv;
    o[1] = ay * inv;
    if ((lane & 15) == 0) s_ws[(long)n * 4 + h] = sa;
}

// ---------------- edge finalize: alpha_norm = ea / (s[dst] + 1e-8) ----------------
__global__ __launch_bounds__(256) void edge_norm_k(const int* __restrict__ ei,
                                                   const int* __restrict__ flag,
                                                   const float* __restrict__ ea_ws,
                                                   const float* __restrict__ s_ws,
                                                   float* __restrict__ anorm) {
    const bool idx64 = (flag[1] != 0);
    const long i = (long)blockIdx.x * 256 + threadIdx.x;
    if (i >= (long)N_EDGES * NH) return;
    const long e = i >> 2;
    const int h = (int)(i & 3);
    const int dst = ld_dst(ei, e, idx64);
    anorm[i] = ea_ws[i] / (s_ws[(long)dst * 4 + h] + 1e-8f);
}

extern "C" void kernel_launch(void* const* d_in, const int* in_sizes, int n_in,
                              void* d_out, int out_size, void* d_ws, size_t ws_size,
                              hipStream_t stream) {
    const void* x      = d_in[0];
    const int*  ei     = (const int*)d_in[1];
    const void* eattr  = d_in[2];
    const void* dw     = d_in[3];
    const void* Wsrc   = d_in[4];
    const void* Wdst   = d_in[5];
    const void* Wedge  = d_in[6];
    const void* att    = d_in[7];
    const void* sscale = d_in[8];

    float* out   = (float*)d_out;                   // reference output dtype: float32
    float* anorm = out + (long)N_NODES * HC;
    float* araw  = anorm + (long)N_EDGES * NH;

    float* ws      = (float*)d_ws;
    int*   flag    = (int*)d_ws;                    // 64-float pad
    float* xsrc    = ws + 64;                       // N*128
    float* xdst    = xsrc + (long)N_NODES * HC;     // N*128
    float* ea      = xdst + (long)N_NODES * HC;     // E*4
    float* s_ws    = ea + (long)N_EDGES * NH;       // N*4
    int*   deg     = (int*)(s_ws + (long)N_NODES * NH);   // N
    int*   row_ptr = deg + N_NODES;                 // N+1
    int*   cursor  = row_ptr + N_NODES + 1;         // N
    int*   eids    = cursor + N_NODES;              // E
    int*   esrc    = eids + N_EDGES;                // E

    detect_k<<<1, 256, 0, stream>>>((const unsigned short*)x, ei, flag);
    zero_deg_k<<<(N_NODES + 255) / 256, 256, 0, stream>>>(deg);
    hist_k<<<(N_EDGES + 255) / 256, 256, 0, stream>>>(ei, flag, deg);
    scan1_k<<<SCAN_BLKS, 256, 0, stream>>>(deg, row_ptr);
    scan2_k<<<1, 256, 0, stream>>>(row_ptr);
    scan3_k<<<SCAN_BLKS, 256, 0, stream>>>(row_ptr, cursor);
    scatter_k<<<(N_EDGES + 255) / 256, 256, 0, stream>>>(ei, flag, cursor, eids, esrc);
    node_gemm_mfma_k<<<1024, 256, 0, stream>>>((const unsigned short*)x,
                                               (const unsigned short*)Wsrc,
                                               (const unsigned short*)Wdst,
                                               flag, xsrc, xdst);
    node_gemm_f32_k<<<N_NODES / 8, 256, 0, stream>>>(x, Wsrc, Wdst, flag, xsrc, xdst);
    edge_alpha_k<<<2048, 256, 0, stream>>>(ei, eattr, dw, Wedge, att, sscale,
                                           flag, xsrc, xdst, ea, araw);
    aggregate_k<<<(N_NODES + 3) / 4, 256, 0, stream>>>(row_ptr, eids, esrc, ea, xsrc, s_ws, out);
    edge_norm_k<<<((long)N_EDGES * NH + 255) / 256, 256, 0, stream>>>(ei, flag, ea, s_ws, anorm);
}

// Round 6
// 671.110 us; speedup vs baseline: 1.6919x; 1.0873x over previous
//
#include <hip/hip_runtime.h>
#include <hip/hip_bf16.h>

#define N_NODES 50000
#define N_EDGES 800000
#define IN_CH   256
#define EDGE_DIM 32
#define NH 4
#define NC 32
#define HC 128   // NH*NC
#define SCAN_BLKS 196   // 196 * 256 = 50176 >= N_NODES
#define EGROUPS (N_EDGES / 64)   // 12500 groups of 64 edges (16 per wave x 4 waves)
#define NTILES (N_NODES / 16)    // 3125 16-node tiles (exact)

typedef __attribute__((ext_vector_type(8))) short bf16x8;
typedef __attribute__((ext_vector_type(4))) float f32x4;

// scan inter-block partials + pre-split transposed weights: device globals
__device__ int g_bsum[256];
__device__ int g_boffs[256];
// W concat [Wsrc | Wdst] transposed: index [c*256 + k], c in [0,256), k in [0,256)
__device__ __align__(16) unsigned short g_wt_hi[256 * 256];
__device__ __align__(16) unsigned short g_wt_lo[256 * 256];

// hw transcendentals (avoid __exp2f/__log2f: glibc math.h name collision)
__device__ __forceinline__ float fexp2(float x) { return __builtin_amdgcn_exp2f(x); }
__device__ __forceinline__ float flog2(float x) { return __builtin_amdgcn_logf(x); }
__device__ __forceinline__ float fexp(float x)  { return __builtin_amdgcn_exp2f(x * 1.44269504089f); }

// fast tanh: 1 - 2/(e^{2x}+1); exact saturation at +/-inf, ~1e-7 abs err
__device__ __forceinline__ float ftanh(float x) {
    const float e = fexp2(x * 2.88539008178f);   // 2*log2(e)
    return 1.0f - 2.0f * __builtin_amdgcn_rcpf(e + 1.0f);
}

// f32 -> bf16 RNE
__device__ __forceinline__ unsigned short f2bf(float f) {
    union { float f; unsigned int u; } v; v.f = f;
    const unsigned int r = v.u + 0x7fffu + ((v.u >> 16) & 1u);
    return (unsigned short)(r >> 16);
}

// split one f32 into truncated-bf16 hi + truncated-bf16 lo (x ~= hi + lo, err ~2^-17)
__device__ __forceinline__ void split8(const float4 a, const float4 b, bf16x8& hi, bf16x8& lo) {
    union { unsigned short us[8]; bf16x8 v; } H, L;
    const float xs[8] = {a.x, a.y, a.z, a.w, b.x, b.y, b.z, b.w};
    #pragma unroll
    for (int e = 0; e < 8; ++e) {
        const unsigned int u = __float_as_uint(xs[e]);
        H.us[e] = (unsigned short)(u >> 16);
        const float lof = xs[e] - __uint_as_float(u & 0xffff0000u);  // exact
        L.us[e] = (unsigned short)(__float_as_uint(lof) >> 16);
    }
    hi = H.v; lo = L.v;
}

// Dual-dtype scalar load: f32 flag selects fp32 vs bf16 interpretation of the raw buffer.
__device__ __forceinline__ float ldf(const void* p, long i, bool f32) {
    return f32 ? ((const float*)p)[i]
               : __bfloat162float(((const __hip_bfloat16*)p)[i]);
}

// Dual-width index loads: idx64 => buffer is int64 [2,E] (values < 2^31, read low words).
__device__ __forceinline__ int ld_src(const int* ei, long e, bool idx64) {
    return idx64 ? ei[2 * e] : ei[e];
}
__device__ __forceinline__ int ld_dst(const int* ei, long e, bool idx64) {
    return idx64 ? ei[2 * ((long)N_EDGES + e)] : ei[(long)N_EDGES + e];
}

// ---------------- dtype detection (runs every call, deterministic) ----------------
__global__ __launch_bounds__(256) void detect_k(const unsigned short* __restrict__ xu,
                                                const int* __restrict__ ei,
                                                int* __restrict__ flag) {
    __shared__ int zc, bc, nz_idx;
    if (threadIdx.x == 0) { zc = 0; bc = 0; nz_idx = 0; }
    __syncthreads();
    int z = 0, b = 0, hi = 0;
    for (int i = threadIdx.x; i < 16384; i += 256) {
        const unsigned short w = xu[2 * i];
        if (w == 0) ++z;
        if ((w & 0x7F80) == 0x7F80) ++b;
    }
    for (int i = threadIdx.x; i < 8192; i += 256)
        if (ei[2 * i + 1] != 0) hi = 1;
    atomicAdd(&zc, z);
    atomicAdd(&bc, b);
    if (hi) atomicAdd(&nz_idx, 1);
    __syncthreads();
    if (threadIdx.x == 0) {
        flag[0] = (zc > 8192 || bc > 0) ? 1 : 0;  // 1 => fp32 float buffers
        flag[1] = (nz_idx == 0) ? 1 : 0;          // 1 => int64 indices
    }
}

// ---------------- CSR build ----------------
__global__ __launch_bounds__(256) void zero_deg_k(int* __restrict__ deg) {
    const int i = blockIdx.x * 256 + threadIdx.x;
    if (i < N_NODES) deg[i] = 0;
}

__global__ __launch_bounds__(256) void hist_k(const int* __restrict__ ei,
                                              const int* __restrict__ flag,
                                              int* __restrict__ deg) {
    const bool idx64 = (flag[1] != 0);
    const long e = (long)blockIdx.x * 256 + threadIdx.x;
    if (e < N_EDGES) atomicAdd(&deg[ld_dst(ei, e, idx64)], 1);
}

// ---- 3-phase parallel exclusive scan ----
__global__ __launch_bounds__(256) void scan1_k(const int* __restrict__ deg,
                                               int* __restrict__ row_ptr) {
    __shared__ int wsum[4];
    const int tid = threadIdx.x;
    const int lane = tid & 63, wid = tid >> 6;
    const int i = blockIdx.x * 256 + tid;
    const int v = (i < N_NODES) ? deg[i] : 0;
    int x = v;
    #pragma unroll
    for (int off = 1; off < 64; off <<= 1) {
        const int t = __shfl_up(x, off);
        if (lane >= off) x += t;
    }
    if (lane == 63) wsum[wid] = x;
    __syncthreads();
    int wpre = 0;
    for (int w = 0; w < wid; ++w) wpre += wsum[w];
    if (i < N_NODES) row_ptr[i] = wpre + x - v;          // block-local exclusive
    if (tid == 0) g_bsum[blockIdx.x] = wsum[0] + wsum[1] + wsum[2] + wsum[3];
}

__global__ __launch_bounds__(256) void scan2_k(int* __restrict__ row_ptr) {
    __shared__ int wsum[4];
    const int tid = threadIdx.x;
    const int lane = tid & 63, wid = tid >> 6;
    const int v = (tid < SCAN_BLKS) ? g_bsum[tid] : 0;
    int x = v;
    #pragma unroll
    for (int off = 1; off < 64; off <<= 1) {
        const int t = __shfl_up(x, off);
        if (lane >= off) x += t;
    }
    if (lane == 63) wsum[wid] = x;
    __syncthreads();
    int wpre = 0;
    for (int w = 0; w < wid; ++w) wpre += wsum[w];
    if (tid < SCAN_BLKS) g_boffs[tid] = wpre + x - v;
    if (tid == 0) row_ptr[N_NODES] = N_EDGES;            // total degree is constant
}

__global__ __launch_bounds__(256) void scan3_k(int* __restrict__ row_ptr,
                                               int* __restrict__ cursor) {
    const int i = blockIdx.x * 256 + threadIdx.x;
    if (i < N_NODES) {
        const int t = row_ptr[i] + g_boffs[blockIdx.x];
        row_ptr[i] = t;
        cursor[i] = t;
    }
}

__global__ __launch_bounds__(256) void scatter_k(const int* __restrict__ ei,
                                                 const int* __restrict__ flag,
                                                 int* __restrict__ cursor,
                                                 int* __restrict__ eids,
                                                 int* __restrict__ esrc) {
    const bool idx64 = (flag[1] != 0);
    const long e = (long)blockIdx.x * 256 + threadIdx.x;
    if (e >= N_EDGES) return;
    const int dst = ld_dst(ei, e, idx64);
    const int src = ld_src(ei, e, idx64);
    const int pos = atomicAdd(&cursor[dst], 1);
    eids[pos] = (int)e;
    esrc[pos] = src;
}

// ---------------- W pre-split (fp32 path): transpose + hi/lo bf16 split ----------------
// g_wt_*[c*256 + k]: c = concat col (c<128 -> Wsrc, else Wdst), k = input channel.
__global__ __launch_bounds__(256) void w_split_k(const float* __restrict__ Wsrc,
                                                 const float* __restrict__ Wdst,
                                                 const int* __restrict__ flag) {
    if (flag[0] == 0) return;        // bf16 inputs: not needed
    const int i = blockIdx.x * 256 + threadIdx.x;   // 65536 elems, one per thread
    const int c = i >> 8;
    const int k = i & 255;
    const float w = (c < HC) ? Wsrc[k * HC + c] : Wdst[k * HC + (c - HC)];
    const unsigned int u = __float_as_uint(w);
    g_wt_hi[i] = (unsigned short)(u >> 16);
    const float lof = w - __uint_as_float(u & 0xffff0000u);
    g_wt_lo[i] = (unsigned short)(__float_as_uint(lof) >> 16);
}

// ---------------- node GEMM (fp32 inputs): split-bf16 MFMA, fp32-accurate ----------------
// x@W = x_hi@w_hi + x_hi@w_lo + x_lo@w_hi (+ O(2^-16) dropped term).
// 8 waves/block; wave w owns cols [w*32, w*32+32) of the 256-wide concat.
// Fragment mapping identical to the validated edge kernel:
//   A: lane l holds x[n0 + (l&15)][ks*32 + 8*(l>>4) + i]
//   B: lane l holds Wcat[ks*32 + 8*(l>>4) + i][cbase + t*16 + (l&15)]
//   C: lane l holds out[n0 + 4*(l>>4) + r][cbase + t*16 + (l&15)]
__global__ __launch_bounds__(512) void node_gemm_f32s_k(const float* __restrict__ x,
                                                        const int* __restrict__ flag,
                                                        float* __restrict__ xsrc,
                                                        float* __restrict__ xdst) {
    if (flag[0] == 0) return;        // bf16 inputs: node_gemm_mfma_k handles it
    const int tid = threadIdx.x;
    const int l   = tid & 63;
    const int wv  = tid >> 6;        // wave 0..7
    const int jj  = l & 15;
    const int hi4 = l >> 4;
    const int cbase = wv * 32;

    // B fragments from pre-split transposed W: contiguous 16B loads
    bf16x8 bhi[8][2], blo[8][2];
    #pragma unroll
    for (int ks = 0; ks < 8; ++ks)
        #pragma unroll
        for (int t = 0; t < 2; ++t) {
            const int off = (cbase + t * 16 + jj) * 256 + ks * 32 + hi4 * 8;
            bhi[ks][t] = *(const bf16x8*)(g_wt_hi + off);
            blo[ks][t] = *(const bf16x8*)(g_wt_lo + off);
        }

    for (int nt = blockIdx.x; nt < NTILES; nt += gridDim.x) {
        const long n0 = (long)nt * 16;
        const float* xr = x + (n0 + jj) * IN_CH;

        f32x4 acc[2];
        acc[0] = (f32x4){0.f, 0.f, 0.f, 0.f};
        acc[1] = (f32x4){0.f, 0.f, 0.f, 0.f};
        #pragma unroll
        for (int ks = 0; ks < 8; ++ks) {
            const float4 a0 = *(const float4*)(xr + ks * 32 + hi4 * 8);
            const float4 a1 = *(const float4*)(xr + ks * 32 + hi4 * 8 + 4);
            bf16x8 ahi, alo;
            split8(a0, a1, ahi, alo);
            #pragma unroll
            for (int t = 0; t < 2; ++t) {
                acc[t] = __builtin_amdgcn_mfma_f32_16x16x32_bf16(ahi, bhi[ks][t], acc[t], 0, 0, 0);
                acc[t] = __builtin_amdgcn_mfma_f32_16x16x32_bf16(ahi, blo[ks][t], acc[t], 0, 0, 0);
                acc[t] = __builtin_amdgcn_mfma_f32_16x16x32_bf16(alo, bhi[ks][t], acc[t], 0, 0, 0);
            }
        }

        #pragma unroll
        for (int t = 0; t < 2; ++t) {
            const int c = cbase + t * 16 + jj;
            float* obase = (c < HC) ? (xsrc + c) : (xdst + (c - HC));
            #pragma unroll
            for (int r = 0; r < 4; ++r)
                obase[(n0 + hi4 * 4 + r) * HC] = acc[t][r];
        }
    }
}

// ---------------- node GEMM (bf16 inputs): MFMA, 16 nodes per wave-tile ----------------
__global__ __launch_bounds__(256) void node_gemm_mfma_k(const unsigned short* __restrict__ x,
                                                        const unsigned short* __restrict__ Wsrc,
                                                        const unsigned short* __restrict__ Wdst,
                                                        const int* __restrict__ flag,
                                                        float* __restrict__ xsrc,
                                                        float* __restrict__ xdst) {
    if (flag[0] != 0) return;        // fp32 inputs: node_gemm_f32s_k handles it
    const int tid = threadIdx.x;
    const int l   = tid & 63;
    const int w   = tid >> 6;
    const int jj  = l & 15;
    const int hi  = l >> 4;
    const int cbase = w * 64;

    bf16x8 bfrag[8][4];
    #pragma unroll
    for (int ks = 0; ks < 8; ++ks)
        #pragma unroll
        for (int t = 0; t < 4; ++t) {
            const int c = cbase + t * 16 + jj;
            const unsigned short* Wp = (c < HC) ? (Wsrc + c) : (Wdst + (c - HC));
            union { unsigned short u[8]; bf16x8 v; } bu;
            #pragma unroll
            for (int i = 0; i < 8; ++i)
                bu.u[i] = Wp[(ks * 32 + hi * 8 + i) * HC];
            bfrag[ks][t] = bu.v;
        }

    for (int nt = blockIdx.x; nt < NTILES; nt += gridDim.x) {
        const long n0 = (long)nt * 16;
        const unsigned short* xr = x + (n0 + jj) * IN_CH + hi * 8;
        bf16x8 afrag[8];
        #pragma unroll
        for (int ks = 0; ks < 8; ++ks)
            afrag[ks] = *(const bf16x8*)(xr + ks * 32);

        f32x4 acc[4];
        #pragma unroll
        for (int t = 0; t < 4; ++t) acc[t] = (f32x4){0.f, 0.f, 0.f, 0.f};
        #pragma unroll
        for (int ks = 0; ks < 8; ++ks)
            #pragma unroll
            for (int t = 0; t < 4; ++t)
                acc[t] = __builtin_amdgcn_mfma_f32_16x16x32_bf16(afrag[ks], bfrag[ks][t], acc[t], 0, 0, 0);

        #pragma unroll
        for (int t = 0; t < 4; ++t) {
            const int c = cbase + t * 16 + jj;
            float* obase = (c < HC) ? (xsrc + c) : (xdst + (c - HC));
            #pragma unroll
            for (int r = 0; r < 4; ++r)
                obase[(n0 + hi * 4 + r) * HC] = acc[t][r];
        }
    }
}

// ---------------- edge alpha pass: MFMA-fused, 16 edges per wave ----------------
__global__ __launch_bounds__(256) void edge_alpha_k(const int* __restrict__ ei,
                                                    const void* __restrict__ eattr,
                                                    const void* __restrict__ dw,
                                                    const void* __restrict__ Wedge,
                                                    const void* __restrict__ att,
                                                    const void* __restrict__ sscale,
                                                    const int* __restrict__ flag,
                                                    const float* __restrict__ xsrc,
                                                    const float* __restrict__ xdst,
                                                    float* __restrict__ ea_ws,
                                                    float* __restrict__ araw_out) {
    const bool f32   = (flag[0] != 0);
    const bool idx64 = (flag[1] != 0);
    __shared__ int   sSrc[4][16];
    __shared__ int   sDst[4][16];
    __shared__ float sDw[4][16];

    const int tid = threadIdx.x;
    const int l   = tid & 63;
    const int wid = tid >> 6;
    const int jj  = l & 15;     // col-within-tile / edge-row for A
    const int hi  = l >> 4;     // lane quarter-group

    // B fragments: W_edge[32][128] columns, loaded once per (persistent) block.
    bf16x8 bfrag[8];
    #pragma unroll
    for (int t = 0; t < 8; ++t) {
        union { unsigned short u[8]; bf16x8 v; } bu;
        #pragma unroll
        for (int i = 0; i < 8; ++i) {
            const int k = hi * 8 + i;
            const int col = t * 16 + jj;
            if (f32) bu.u[i] = f2bf(((const float*)Wedge)[k * HC + col]);
            else     bu.u[i] = ((const unsigned short*)Wedge)[k * HC + col];
        }
        bfrag[t] = bu.v;
    }
    float attv[8];
    #pragma unroll
    for (int t = 0; t < 8; ++t) attv[t] = ldf(att, t * 16 + jj, f32);
    const float ssv = ldf(sscale, l & 3, f32);

    for (long g = blockIdx.x; g < EGROUPS; g += (long)gridDim.x) {
        const long e0 = g * 64 + (long)wid * 16;

        // stage per-edge scalars (16 edges) into wave-private LDS
        if (l < 16)      sSrc[wid][l]      = ld_src(ei, e0 + l, idx64);
        else if (l < 32) sDst[wid][l - 16] = ld_dst(ei, e0 + (l - 16), idx64);
        else if (l < 48) sDw[wid][l - 32]  = ldf(dw, e0 + (l - 32), f32);
        __builtin_amdgcn_wave_barrier();

        // A fragment: 8 contiguous k-values of edge (e0 + jj)
        bf16x8 afrag;
        if (f32) {
            const float* ar = (const float*)eattr + (e0 + jj) * EDGE_DIM + hi * 8;
            const float4 p0 = *(const float4*)ar;
            const float4 p1 = *(const float4*)(ar + 4);
            union { unsigned short u[8]; bf16x8 v; } au;
            au.u[0] = f2bf(p0.x); au.u[1] = f2bf(p0.y); au.u[2] = f2bf(p0.z); au.u[3] = f2bf(p0.w);
            au.u[4] = f2bf(p1.x); au.u[5] = f2bf(p1.y); au.u[6] = f2bf(p1.z); au.u[7] = f2bf(p1.w);
            afrag = au.v;
        } else {
            afrag = *(const bf16x8*)((const unsigned short*)eattr + (e0 + jj) * EDGE_DIM + hi * 8);
        }

        // e_feat[16 edges][128 cols] via 8 MFMAs (K=32 in one shot each)
        const f32x4 zero = {0.f, 0.f, 0.f, 0.f};
        f32x4 acc[8];
        #pragma unroll
        for (int t = 0; t < 8; ++t)
            acc[t] = __builtin_amdgcn_mfma_f32_16x16x32_bf16(afrag, bfrag[t], zero, 0, 0, 0);

        // tanh + att-weighted per-head partial sums
        float hsum[4][4] = {{0,0,0,0},{0,0,0,0},{0,0,0,0},{0,0,0,0}};
        #pragma unroll
        for (int r = 0; r < 4; ++r) {
            const int sI = sSrc[wid][hi * 4 + r];   // LDS broadcast within group
            const int dI = sDst[wid][hi * 4 + r];
            const float* bs = xsrc + (long)sI * HC + jj;
            const float* bd = xdst + (long)dI * HC + jj;
            float xsv[8], xdv[8];
            #pragma unroll
            for (int t = 0; t < 8; ++t) xsv[t] = bs[t * 16];
            #pragma unroll
            for (int t = 0; t < 8; ++t) xdv[t] = bd[t * 16];
            #pragma unroll
            for (int t = 0; t < 8; ++t) {
                const float v = ftanh(acc[t][r] + xsv[t] + xdv[t]) * attv[t];
                hsum[r][t >> 1] += v;
            }
        }

        // reduce each (edge r, head h) over the 16 lanes of the group
        #pragma unroll
        for (int r = 0; r < 4; ++r)
            #pragma unroll
            for (int h2 = 0; h2 < 4; ++h2) {
                float v = hsum[r][h2];
                v += __shfl_xor(v, 1);
                v += __shfl_xor(v, 2);
                v += __shfl_xor(v, 4);
                v += __shfl_xor(v, 8);
                hsum[r][h2] = v;
            }

        // lane jj handles (edge r_sel = jj>>2, head hh = jj&3): coalesced 256B stores
        float val = hsum[0][0];
        #pragma unroll
        for (int r = 0; r < 4; ++r)
            #pragma unroll
            for (int h2 = 0; h2 < 4; ++h2)
                if (jj == r * 4 + h2) val = hsum[r][h2];

        const int r_sel = jj >> 2;
        const long er = e0 + hi * 4 + r_sel;
        const float dwv = sDw[wid][hi * 4 + r_sel];
        araw_out[er * 4 + (jj & 3)] = val;                    // pre-decay logit
        const float d = fexp2(ssv * flog2(dwv));              // dwv ** ss
        ea_ws[er * 4 + (jj & 3)] = fexp(val * d);
        __builtin_amdgcn_wave_barrier();
    }
}

// ---------------- CSR aggregation: one wave per dst node, no atomics ----------------
__global__ __launch_bounds__(256) void aggregate_k(const int* __restrict__ row_ptr,
                                                   const int* __restrict__ eids,
                                                   const int* __restrict__ esrc,
                                                   const float* __restrict__ ea_ws,
                                                   const float* __restrict__ xsrc,
                                                   float* __restrict__ s_ws,
                                                   float* __restrict__ out) {
    const int tid = threadIdx.x;
    const int lane = tid & 63;
    const int n = blockIdx.x * 4 + (tid >> 6);
    if (n >= N_NODES) return;
    const int h = lane >> 4;

    const int p0 = row_ptr[n];
    const int p1 = row_ptr[n + 1];

    float ax = 0.0f, ay = 0.0f, sa = 0.0f;
    for (int p = p0; p < p1; ++p) {
        const int e = eids[p];
        const int src = esrc[p];
        const float w = ea_ws[(long)e * 4 + h];
        const float2 xv = *(const float2*)(xsrc + (long)src * HC + (lane << 1));
        ax += w * xv.x;
        ay += w * xv.y;
        sa += w;
    }
    const float inv = 1.0f / (sa + 1e-8f);
    float* o = out + (long)n * HC + (lane << 1);
    o[0] = ax * inv;
    o[1] = ay * inv;
    if ((lane & 15) == 0) s_ws[(long)n * 4 + h] = sa;
}

// ---------------- edge finalize: alpha_norm = ea / (s[dst] + 1e-8) ----------------
__global__ __launch_bounds__(256) void edge_norm_k(const int* __restrict__ ei,
                                                   const int* __restrict__ flag,
                                                   const float* __restrict__ ea_ws,
                                                   const float* __restrict__ s_ws,
                                                   float* __restrict__ anorm) {
    const bool idx64 = (flag[1] != 0);
    const long i = (long)blockIdx.x * 256 + threadIdx.x;
    if (i >= (long)N_EDGES * NH) return;
    const long e = i >> 2;
    const int h = (int)(i & 3);
    const int dst = ld_dst(ei, e, idx64);
    anorm[i] = ea_ws[i] / (s_ws[(long)dst * 4 + h] + 1e-8f);
}

extern "C" void kernel_launch(void* const* d_in, const int* in_sizes, int n_in,
                              void* d_out, int out_size, void* d_ws, size_t ws_size,
                              hipStream_t stream) {
    const void* x      = d_in[0];
    const int*  ei     = (const int*)d_in[1];
    const void* eattr  = d_in[2];
    const void* dw     = d_in[3];
    const void* Wsrc   = d_in[4];
    const void* Wdst   = d_in[5];
    const void* Wedge  = d_in[6];
    const void* att    = d_in[7];
    const void* sscale = d_in[8];

    float* out   = (float*)d_out;                   // reference output dtype: float32
    float* anorm = out + (long)N_NODES * HC;
    float* araw  = anorm + (long)N_EDGES * NH;

    float* ws      = (float*)d_ws;
    int*   flag    = (int*)d_ws;                    // 64-float pad
    float* xsrc    = ws + 64;                       // N*128
    float* xdst    = xsrc + (long)N_NODES * HC;     // N*128
    float* ea      = xdst + (long)N_NODES * HC;     // E*4
    float* s_ws    = ea + (long)N_EDGES * NH;       // N*4
    int*   deg     = (int*)(s_ws + (long)N_NODES * NH);   // N
    int*   row_ptr = deg + N_NODES;                 // N+1
    int*   cursor  = row_ptr + N_NODES + 1;         // N
    int*   eids    = cursor + N_NODES;              // E
    int*   esrc    = eids + N_EDGES;                // E

    detect_k<<<1, 256, 0, stream>>>((const unsigned short*)x, ei, flag);
    zero_deg_k<<<(N_NODES + 255) / 256, 256, 0, stream>>>(deg);
    hist_k<<<(N_EDGES + 255) / 256, 256, 0, stream>>>(ei, flag, deg);
    scan1_k<<<SCAN_BLKS, 256, 0, stream>>>(deg, row_ptr);
    scan2_k<<<1, 256, 0, stream>>>(row_ptr);
    scan3_k<<<SCAN_BLKS, 256, 0, stream>>>(row_ptr, cursor);
    scatter_k<<<(N_EDGES + 255) / 256, 256, 0, stream>>>(ei, flag, cursor, eids, esrc);
    w_split_k<<<256, 256, 0, stream>>>((const float*)Wsrc, (const float*)Wdst, flag);
    node_gemm_f32s_k<<<512, 512, 0, stream>>>((const float*)x, flag, xsrc, xdst);
    node_gemm_mfma_k<<<1024, 256, 0, stream>>>((const unsigned short*)x,
                                               (const unsigned short*)Wsrc,
                                               (const unsigned short*)Wdst,
                                               flag, xsrc, xdst);
    edge_alpha_k<<<2048, 256, 0, stream>>>(ei, eattr, dw, Wedge, att, sscale,
                                           flag, xsrc, xdst, ea, araw);
    aggregate_k<<<(N_NODES + 3) / 4, 256, 0, stream>>>(row_ptr, eids, esrc, ea, xsrc, s_ws, out);
    edge_norm_k<<<((long)N_EDGES * NH + 255) / 256, 256, 0, stream>>>(ei, flag, ea, s_ws, anorm);
}

// Round 7
// 664.456 us; speedup vs baseline: 1.7088x; 1.0100x over previous
//
#include <hip/hip_runtime.h>
#include <hip/hip_bf16.h>

#define N_NODES 50000
#define N_EDGES 800000
#define IN_CH   256
#define EDGE_DIM 32
#define NH 4
#define NC 32
#define HC 128   // NH*NC
#define SCAN_BLKS 196   // 196 * 256 = 50176 >= N_NODES
#define NTILES (N_NODES / 16)    // 3125 16-node tiles (exact)

typedef __attribute__((ext_vector_type(8))) short bf16x8;
typedef __attribute__((ext_vector_type(4))) float f32x4;

// scan inter-block partials + pre-split transposed weights: device globals
__device__ int g_bsum[256];
__device__ int g_boffs[256];
// W concat [Wsrc | Wdst] transposed: index [c*256 + k], c in [0,256), k in [0,256)
__device__ __align__(16) unsigned short g_wt_hi[256 * 256];
__device__ __align__(16) unsigned short g_wt_lo[256 * 256];

// hw transcendentals (avoid __exp2f/__log2f: glibc math.h name collision)
__device__ __forceinline__ float fexp2(float x) { return __builtin_amdgcn_exp2f(x); }
__device__ __forceinline__ float flog2(float x) { return __builtin_amdgcn_logf(x); }
__device__ __forceinline__ float fexp(float x)  { return __builtin_amdgcn_exp2f(x * 1.44269504089f); }

// fast tanh: 1 - 2/(e^{2x}+1); exact saturation at +/-inf, ~1e-7 abs err
__device__ __forceinline__ float ftanh(float x) {
    const float e = fexp2(x * 2.88539008178f);   // 2*log2(e)
    return 1.0f - 2.0f * __builtin_amdgcn_rcpf(e + 1.0f);
}

// f32 -> bf16 RNE
__device__ __forceinline__ unsigned short f2bf(float f) {
    union { float f; unsigned int u; } v; v.f = f;
    const unsigned int r = v.u + 0x7fffu + ((v.u >> 16) & 1u);
    return (unsigned short)(r >> 16);
}

// split f32x8 into truncated-bf16 hi + bf16 lo (x ~= hi + lo, err ~2^-17)
__device__ __forceinline__ void split8(const float4 a, const float4 b, bf16x8& hi, bf16x8& lo) {
    union { unsigned short us[8]; bf16x8 v; } H, L;
    const float xs[8] = {a.x, a.y, a.z, a.w, b.x, b.y, b.z, b.w};
    #pragma unroll
    for (int e = 0; e < 8; ++e) {
        const unsigned int u = __float_as_uint(xs[e]);
        H.us[e] = (unsigned short)(u >> 16);
        const float lof = xs[e] - __uint_as_float(u & 0xffff0000u);  // exact
        L.us[e] = (unsigned short)(__float_as_uint(lof) >> 16);
    }
    hi = H.v; lo = L.v;
}

// Dual-dtype scalar load: f32 flag selects fp32 vs bf16 interpretation of the raw buffer.
__device__ __forceinline__ float ldf(const void* p, long i, bool f32) {
    return f32 ? ((const float*)p)[i]
               : __bfloat162float(((const __hip_bfloat16*)p)[i]);
}

// Dual-width index loads: idx64 => buffer is int64 [2,E] (values < 2^31, read low words).
__device__ __forceinline__ int ld_src(const int* ei, long e, bool idx64) {
    return idx64 ? ei[2 * e] : ei[e];
}
__device__ __forceinline__ int ld_dst(const int* ei, long e, bool idx64) {
    return idx64 ? ei[2 * ((long)N_EDGES + e)] : ei[(long)N_EDGES + e];
}

// ---------------- dtype detection (runs every call, deterministic) ----------------
__global__ __launch_bounds__(256) void detect_k(const unsigned short* __restrict__ xu,
                                                const int* __restrict__ ei,
                                                int* __restrict__ flag) {
    __shared__ int zc, bc, nz_idx;
    if (threadIdx.x == 0) { zc = 0; bc = 0; nz_idx = 0; }
    __syncthreads();
    int z = 0, b = 0, hi = 0;
    for (int i = threadIdx.x; i < 4096; i += 256) {
        const unsigned short w = xu[2 * i];
        if (w == 0) ++z;
        if ((w & 0x7F80) == 0x7F80) ++b;
    }
    for (int i = threadIdx.x; i < 2048; i += 256)
        if (ei[2 * i + 1] != 0) hi = 1;
    atomicAdd(&zc, z);
    atomicAdd(&bc, b);
    if (hi) atomicAdd(&nz_idx, 1);
    __syncthreads();
    if (threadIdx.x == 0) {
        flag[0] = (zc > 2048 || bc > 0) ? 1 : 0;  // 1 => fp32 float buffers
        flag[1] = (nz_idx == 0) ? 1 : 0;          // 1 => int64 indices
    }
}

// ---------------- CSR build ----------------
__global__ __launch_bounds__(256) void zero_deg_k(int* __restrict__ deg) {
    const int i = blockIdx.x * 256 + threadIdx.x;
    if (i < N_NODES) deg[i] = 0;
}

__global__ __launch_bounds__(256) void hist_k(const int* __restrict__ ei,
                                              const int* __restrict__ flag,
                                              int* __restrict__ deg) {
    const bool idx64 = (flag[1] != 0);
    const long e = (long)blockIdx.x * 256 + threadIdx.x;
    if (e < N_EDGES) atomicAdd(&deg[ld_dst(ei, e, idx64)], 1);
}

// ---- 3-phase parallel exclusive scan ----
__global__ __launch_bounds__(256) void scan1_k(const int* __restrict__ deg,
                                               int* __restrict__ row_ptr) {
    __shared__ int wsum[4];
    const int tid = threadIdx.x;
    const int lane = tid & 63, wid = tid >> 6;
    const int i = blockIdx.x * 256 + tid;
    const int v = (i < N_NODES) ? deg[i] : 0;
    int x = v;
    #pragma unroll
    for (int off = 1; off < 64; off <<= 1) {
        const int t = __shfl_up(x, off);
        if (lane >= off) x += t;
    }
    if (lane == 63) wsum[wid] = x;
    __syncthreads();
    int wpre = 0;
    for (int w = 0; w < wid; ++w) wpre += wsum[w];
    if (i < N_NODES) row_ptr[i] = wpre + x - v;          // block-local exclusive
    if (tid == 0) g_bsum[blockIdx.x] = wsum[0] + wsum[1] + wsum[2] + wsum[3];
}

__global__ __launch_bounds__(256) void scan2_k(int* __restrict__ row_ptr) {
    __shared__ int wsum[4];
    const int tid = threadIdx.x;
    const int lane = tid & 63, wid = tid >> 6;
    const int v = (tid < SCAN_BLKS) ? g_bsum[tid] : 0;
    int x = v;
    #pragma unroll
    for (int off = 1; off < 64; off <<= 1) {
        const int t = __shfl_up(x, off);
        if (lane >= off) x += t;
    }
    if (lane == 63) wsum[wid] = x;
    __syncthreads();
    int wpre = 0;
    for (int w = 0; w < wid; ++w) wpre += wsum[w];
    if (tid < SCAN_BLKS) g_boffs[tid] = wpre + x - v;
    if (tid == 0) row_ptr[N_NODES] = N_EDGES;            // total degree is constant
}

__global__ __launch_bounds__(256) void scan3_k(int* __restrict__ row_ptr,
                                               int* __restrict__ cursor) {
    const int i = blockIdx.x * 256 + threadIdx.x;
    if (i < N_NODES) {
        const int t = row_ptr[i] + g_boffs[blockIdx.x];
        row_ptr[i] = t;
        cursor[i] = t;
    }
}

__global__ __launch_bounds__(256) void scatter_k(const int* __restrict__ ei,
                                                 const int* __restrict__ flag,
                                                 int* __restrict__ cursor,
                                                 int* __restrict__ eids,
                                                 int* __restrict__ esrc) {
    const bool idx64 = (flag[1] != 0);
    const long e = (long)blockIdx.x * 256 + threadIdx.x;
    if (e >= N_EDGES) return;
    const int dst = ld_dst(ei, e, idx64);
    const int src = ld_src(ei, e, idx64);
    const int pos = atomicAdd(&cursor[dst], 1);
    eids[pos] = (int)e;
    esrc[pos] = src;
}

// ---------------- W pre-split (fp32 path): transpose + hi/lo bf16 split ----------------
__global__ __launch_bounds__(256) void w_split_k(const float* __restrict__ Wsrc,
                                                 const float* __restrict__ Wdst,
                                                 const int* __restrict__ flag) {
    if (flag[0] == 0) return;        // bf16 inputs: not needed
    const int i = blockIdx.x * 256 + threadIdx.x;   // 65536 elems, one per thread
    const int c = i >> 8;
    const int k = i & 255;
    const float w = (c < HC) ? Wsrc[k * HC + c] : Wdst[k * HC + (c - HC)];
    const unsigned int u = __float_as_uint(w);
    g_wt_hi[i] = (unsigned short)(u >> 16);
    const float lof = w - __uint_as_float(u & 0xffff0000u);
    g_wt_lo[i] = (unsigned short)(__float_as_uint(lof) >> 16);
}

// ---------------- node GEMM (fp32 inputs): split-bf16 MFMA, fp32-accurate ----------------
__global__ __launch_bounds__(512) void node_gemm_f32s_k(const float* __restrict__ x,
                                                        const int* __restrict__ flag,
                                                        float* __restrict__ xsrc,
                                                        float* __restrict__ xdst) {
    if (flag[0] == 0) return;        // bf16 inputs: node_gemm_mfma_k handles it
    const int tid = threadIdx.x;
    const int l   = tid & 63;
    const int wv  = tid >> 6;        // wave 0..7
    const int jj  = l & 15;
    const int hi4 = l >> 4;
    const int cbase = wv * 32;

    bf16x8 bhi[8][2], blo[8][2];
    #pragma unroll
    for (int ks = 0; ks < 8; ++ks)
        #pragma unroll
        for (int t = 0; t < 2; ++t) {
            const int off = (cbase + t * 16 + jj) * 256 + ks * 32 + hi4 * 8;
            bhi[ks][t] = *(const bf16x8*)(g_wt_hi + off);
            blo[ks][t] = *(const bf16x8*)(g_wt_lo + off);
        }

    for (int nt = blockIdx.x; nt < NTILES; nt += gridDim.x) {
        const long n0 = (long)nt * 16;
        const float* xr = x + (n0 + jj) * IN_CH;

        f32x4 acc[2];
        acc[0] = (f32x4){0.f, 0.f, 0.f, 0.f};
        acc[1] = (f32x4){0.f, 0.f, 0.f, 0.f};
        #pragma unroll
        for (int ks = 0; ks < 8; ++ks) {
            const float4 a0 = *(const float4*)(xr + ks * 32 + hi4 * 8);
            const float4 a1 = *(const float4*)(xr + ks * 32 + hi4 * 8 + 4);
            bf16x8 ahi, alo;
            split8(a0, a1, ahi, alo);
            #pragma unroll
            for (int t = 0; t < 2; ++t) {
                acc[t] = __builtin_amdgcn_mfma_f32_16x16x32_bf16(ahi, bhi[ks][t], acc[t], 0, 0, 0);
                acc[t] = __builtin_amdgcn_mfma_f32_16x16x32_bf16(ahi, blo[ks][t], acc[t], 0, 0, 0);
                acc[t] = __builtin_amdgcn_mfma_f32_16x16x32_bf16(alo, bhi[ks][t], acc[t], 0, 0, 0);
            }
        }

        #pragma unroll
        for (int t = 0; t < 2; ++t) {
            const int c = cbase + t * 16 + jj;
            float* obase = (c < HC) ? (xsrc + c) : (xdst + (c - HC));
            #pragma unroll
            for (int r = 0; r < 4; ++r)
                obase[(n0 + hi4 * 4 + r) * HC] = acc[t][r];
        }
    }
}

// ---------------- node GEMM (bf16 inputs): MFMA ----------------
__global__ __launch_bounds__(256) void node_gemm_mfma_k(const unsigned short* __restrict__ x,
                                                        const unsigned short* __restrict__ Wsrc,
                                                        const unsigned short* __restrict__ Wdst,
                                                        const int* __restrict__ flag,
                                                        float* __restrict__ xsrc,
                                                        float* __restrict__ xdst) {
    if (flag[0] != 0) return;        // fp32 inputs: node_gemm_f32s_k handles it
    const int tid = threadIdx.x;
    const int l   = tid & 63;
    const int w   = tid >> 6;
    const int jj  = l & 15;
    const int hi  = l >> 4;
    const int cbase = w * 64;

    bf16x8 bfrag[8][4];
    #pragma unroll
    for (int ks = 0; ks < 8; ++ks)
        #pragma unroll
        for (int t = 0; t < 4; ++t) {
            const int c = cbase + t * 16 + jj;
            const unsigned short* Wp = (c < HC) ? (Wsrc + c) : (Wdst + (c - HC));
            union { unsigned short u[8]; bf16x8 v; } bu;
            #pragma unroll
            for (int i = 0; i < 8; ++i)
                bu.u[i] = Wp[(ks * 32 + hi * 8 + i) * HC];
            bfrag[ks][t] = bu.v;
        }

    for (int nt = blockIdx.x; nt < NTILES; nt += gridDim.x) {
        const long n0 = (long)nt * 16;
        const unsigned short* xr = x + (n0 + jj) * IN_CH + hi * 8;
        bf16x8 afrag[8];
        #pragma unroll
        for (int ks = 0; ks < 8; ++ks)
            afrag[ks] = *(const bf16x8*)(xr + ks * 32);

        f32x4 acc[4];
        #pragma unroll
        for (int t = 0; t < 4; ++t) acc[t] = (f32x4){0.f, 0.f, 0.f, 0.f};
        #pragma unroll
        for (int ks = 0; ks < 8; ++ks)
            #pragma unroll
            for (int t = 0; t < 4; ++t)
                acc[t] = __builtin_amdgcn_mfma_f32_16x16x32_bf16(afrag[ks], bfrag[ks][t], acc[t], 0, 0, 0);

        #pragma unroll
        for (int t = 0; t < 4; ++t) {
            const int c = cbase + t * 16 + jj;
            float* obase = (c < HC) ? (xsrc + c) : (xdst + (c - HC));
            #pragma unroll
            for (int r = 0; r < 4; ++r)
                obase[(n0 + hi * 4 + r) * HC] = acc[t][r];
        }
    }
}

// ---------------- FUSED edge-alpha + aggregation: one wave per dst node ----------------
// CSR order. Per node: xdst row loaded once; per 16-edge tile, MFMA e_feat (validated
// mapping), tanh+att reduce -> alpha, ea=exp(alpha*dw^ss); xsrc rows gathered ONCE and
// reused for the ea*xs aggregation. Outputs: out (normalized), ea_ws, araw, s_ws.
__global__ __launch_bounds__(256) void fused_edge_agg_k(const int* __restrict__ row_ptr,
                                                        const int* __restrict__ eids,
                                                        const int* __restrict__ esrc,
                                                        const void* __restrict__ eattr,
                                                        const void* __restrict__ dw,
                                                        const void* __restrict__ Wedge,
                                                        const void* __restrict__ att,
                                                        const void* __restrict__ sscale,
                                                        const int* __restrict__ flag,
                                                        const float* __restrict__ xsrc,
                                                        const float* __restrict__ xdst,
                                                        float* __restrict__ ea_ws,
                                                        float* __restrict__ araw_out,
                                                        float* __restrict__ s_ws,
                                                        float* __restrict__ out) {
    const bool f32 = (flag[0] != 0);
    __shared__ int   sEid[4][16];
    __shared__ int   sSrc[4][16];
    __shared__ float sDw[4][16];

    const int tid = threadIdx.x;
    const int l   = tid & 63;
    const int wid = tid >> 6;
    const int jj  = l & 15;     // col-within-tile / A-edge index
    const int hi  = l >> 4;     // lane quarter-group

    // B fragments: W_edge[32][128], loaded once per persistent block
    bf16x8 bfrag[8];
    #pragma unroll
    for (int t = 0; t < 8; ++t) {
        union { unsigned short u[8]; bf16x8 v; } bu;
        #pragma unroll
        for (int i = 0; i < 8; ++i) {
            const int k = hi * 8 + i;
            const int col = t * 16 + jj;
            if (f32) bu.u[i] = f2bf(((const float*)Wedge)[k * HC + col]);
            else     bu.u[i] = ((const unsigned short*)Wedge)[k * HC + col];
        }
        bfrag[t] = bu.v;
    }
    float attv[8];
    #pragma unroll
    for (int t = 0; t < 8; ++t) attv[t] = ldf(att, t * 16 + jj, f32);
    float ss4[4];
    #pragma unroll
    for (int h2 = 0; h2 < 4; ++h2) ss4[h2] = ldf(sscale, h2, f32);

    const int nwaves = gridDim.x * 4;
    for (int n = blockIdx.x * 4 + wid; n < N_NODES; n += nwaves) {
        const int p0 = row_ptr[n];
        const int p1 = row_ptr[n + 1];

        float xdv[8];
        #pragma unroll
        for (int t = 0; t < 8; ++t) xdv[t] = xdst[(long)n * HC + jj + t * 16];

        float ax[8] = {0,0,0,0,0,0,0,0};
        float sal[4] = {0,0,0,0};

        for (int base = p0; base < p1; base += 16) {
            if (l < 16) {
                const int p = min(base + l, p1 - 1);
                const int e = eids[p];
                sEid[wid][l] = e;
                sSrc[wid][l] = esrc[p];
                sDw[wid][l]  = ldf(dw, e, f32);
            }
            __builtin_amdgcn_wave_barrier();

            // A fragment: eattr row of edge sEid[jj], k-chunk hi*8..hi*8+8
            const long eA = sEid[wid][jj];
            bf16x8 afrag;
            if (f32) {
                const float* ar = (const float*)eattr + eA * EDGE_DIM + hi * 8;
                const float4 q0 = *(const float4*)ar;
                const float4 q1 = *(const float4*)(ar + 4);
                union { unsigned short u[8]; bf16x8 v; } au;
                au.u[0] = f2bf(q0.x); au.u[1] = f2bf(q0.y); au.u[2] = f2bf(q0.z); au.u[3] = f2bf(q0.w);
                au.u[4] = f2bf(q1.x); au.u[5] = f2bf(q1.y); au.u[6] = f2bf(q1.z); au.u[7] = f2bf(q1.w);
                afrag = au.v;
            } else {
                afrag = *(const bf16x8*)((const unsigned short*)eattr + eA * EDGE_DIM + hi * 8);
            }

            const f32x4 zero = {0.f, 0.f, 0.f, 0.f};
            f32x4 acc[8];
            #pragma unroll
            for (int t = 0; t < 8; ++t)
                acc[t] = __builtin_amdgcn_mfma_f32_16x16x32_bf16(afrag, bfrag[t], zero, 0, 0, 0);

            // gather xsrc rows (kept for aggregation), tanh + att partial sums
            float xsv[4][8];
            float hsum[4][4] = {{0,0,0,0},{0,0,0,0},{0,0,0,0},{0,0,0,0}};
            #pragma unroll
            for (int r = 0; r < 4; ++r) {
                const int sI = sSrc[wid][hi * 4 + r];
                const float* bs = xsrc + (long)sI * HC + jj;
                #pragma unroll
                for (int t = 0; t < 8; ++t) xsv[r][t] = bs[t * 16];
                #pragma unroll
                for (int t = 0; t < 8; ++t) {
                    const float v = ftanh(acc[t][r] + xsv[r][t] + xdv[t]) * attv[t];
                    hsum[r][t >> 1] += v;
                }
            }

            // reduce over the 16 lanes of the group (all lanes end with full sums)
            #pragma unroll
            for (int r = 0; r < 4; ++r)
                #pragma unroll
                for (int h2 = 0; h2 < 4; ++h2) {
                    float v = hsum[r][h2];
                    v += __shfl_xor(v, 1);
                    v += __shfl_xor(v, 2);
                    v += __shfl_xor(v, 4);
                    v += __shfl_xor(v, 8);
                    hsum[r][h2] = v;
                }

            // ea for all (r, head), masked by tile validity
            float eaV[4][4];
            #pragma unroll
            for (int r = 0; r < 4; ++r) {
                const bool valid = (base + hi * 4 + r) < p1;
                const float lg = flog2(sDw[wid][hi * 4 + r]);
                #pragma unroll
                for (int h2 = 0; h2 < 4; ++h2) {
                    const float d = fexp2(ss4[h2] * lg);
                    eaV[r][h2] = valid ? fexp(hsum[r][h2] * d) : 0.0f;
                }
            }

            // scattered per-edge stores: lane jj <-> (r_sel = jj>>2, head = jj&3)
            {
                const int r_sel = jj >> 2, hh = jj & 3;
                if (base + hi * 4 + r_sel < p1) {
                    float pval = hsum[0][0], eval = eaV[0][0];
                    #pragma unroll
                    for (int r = 0; r < 4; ++r)
                        #pragma unroll
                        for (int h2 = 0; h2 < 4; ++h2)
                            if (jj == r * 4 + h2) { pval = hsum[r][h2]; eval = eaV[r][h2]; }
                    const long e2 = sEid[wid][hi * 4 + r_sel];
                    araw_out[e2 * 4 + hh] = pval;
                    ea_ws[e2 * 4 + hh]    = eval;
                }
            }

            // aggregation: ax[c] += ea * xs[c]; sal[h] += ea (group-local 4 edges)
            #pragma unroll
            for (int r = 0; r < 4; ++r) {
                #pragma unroll
                for (int t = 0; t < 8; ++t)
                    ax[t] += eaV[r][t >> 1] * xsv[r][t];
                #pragma unroll
                for (int h2 = 0; h2 < 4; ++h2) sal[h2] += eaV[r][h2];
            }
            __builtin_amdgcn_wave_barrier();
        }

        // combine the 4 lane-groups (lane bits 4,5)
        #pragma unroll
        for (int t = 0; t < 8; ++t) {
            ax[t] += __shfl_xor(ax[t], 16);
            ax[t] += __shfl_xor(ax[t], 32);
        }
        #pragma unroll
        for (int h2 = 0; h2 < 4; ++h2) {
            sal[h2] += __shfl_xor(sal[h2], 16);
            sal[h2] += __shfl_xor(sal[h2], 32);
        }
        float inv[4];
        #pragma unroll
        for (int h2 = 0; h2 < 4; ++h2) inv[h2] = 1.0f / (sal[h2] + 1e-8f);

        // out row: lane writes channels jj + 16*(hi*2) and jj + 16*(hi*2+1)
        {
            const int t0 = hi * 2, t1 = t0 + 1;
            out[(long)n * HC + jj + 16 * t0] = ax[t0] * inv[t0 >> 1];
            out[(long)n * HC + jj + 16 * t1] = ax[t1] * inv[t1 >> 1];
        }
        if (l < 4) s_ws[(long)n * 4 + l] = sal[l];
    }
}

// ---------------- edge finalize: alpha_norm = ea / (s[dst] + 1e-8) ----------------
__global__ __launch_bounds__(256) void edge_norm_k(const int* __restrict__ ei,
                                                   const int* __restrict__ flag,
                                                   const float* __restrict__ ea_ws,
                                                   const float* __restrict__ s_ws,
                                                   float* __restrict__ anorm) {
    const bool idx64 = (flag[1] != 0);
    const long i = (long)blockIdx.x * 256 + threadIdx.x;
    if (i >= (long)N_EDGES * NH) return;
    const long e = i >> 2;
    const int h = (int)(i & 3);
    const int dst = ld_dst(ei, e, idx64);
    anorm[i] = ea_ws[i] / (s_ws[(long)dst * 4 + h] + 1e-8f);
}

extern "C" void kernel_launch(void* const* d_in, const int* in_sizes, int n_in,
                              void* d_out, int out_size, void* d_ws, size_t ws_size,
                              hipStream_t stream) {
    const void* x      = d_in[0];
    const int*  ei     = (const int*)d_in[1];
    const void* eattr  = d_in[2];
    const void* dw     = d_in[3];
    const void* Wsrc   = d_in[4];
    const void* Wdst   = d_in[5];
    const void* Wedge  = d_in[6];
    const void* att    = d_in[7];
    const void* sscale = d_in[8];

    float* out   = (float*)d_out;                   // reference output dtype: float32
    float* anorm = out + (long)N_NODES * HC;
    float* araw  = anorm + (long)N_EDGES * NH;

    float* ws      = (float*)d_ws;
    int*   flag    = (int*)d_ws;                    // 64-float pad
    float* xsrc    = ws + 64;                       // N*128
    float* xdst    = xsrc + (long)N_NODES * HC;     // N*128
    float* ea      = xdst + (long)N_NODES * HC;     // E*4
    float* s_ws    = ea + (long)N_EDGES * NH;       // N*4
    int*   deg     = (int*)(s_ws + (long)N_NODES * NH);   // N
    int*   row_ptr = deg + N_NODES;                 // N+1
    int*   cursor  = row_ptr + N_NODES + 1;         // N
    int*   eids    = cursor + N_NODES;              // E
    int*   esrc    = eids + N_EDGES;                // E

    detect_k<<<1, 256, 0, stream>>>((const unsigned short*)x, ei, flag);
    zero_deg_k<<<(N_NODES + 255) / 256, 256, 0, stream>>>(deg);
    hist_k<<<(N_EDGES + 255) / 256, 256, 0, stream>>>(ei, flag, deg);
    scan1_k<<<SCAN_BLKS, 256, 0, stream>>>(deg, row_ptr);
    scan2_k<<<1, 256, 0, stream>>>(row_ptr);
    scan3_k<<<SCAN_BLKS, 256, 0, stream>>>(row_ptr, cursor);
    scatter_k<<<(N_EDGES + 255) / 256, 256, 0, stream>>>(ei, flag, cursor, eids, esrc);
    w_split_k<<<256, 256, 0, stream>>>((const float*)Wsrc, (const float*)Wdst, flag);
    node_gemm_f32s_k<<<512, 512, 0, stream>>>((const float*)x, flag, xsrc, xdst);
    node_gemm_mfma_k<<<1024, 256, 0, stream>>>((const unsigned short*)x,
                                               (const unsigned short*)Wsrc,
                                               (const unsigned short*)Wdst,
                                               flag, xsrc, xdst);
    fused_edge_agg_k<<<2048, 256, 0, stream>>>(row_ptr, eids, esrc, eattr, dw, Wedge,
                                               att, sscale, flag, xsrc, xdst,
                                               ea, araw, s_ws, out);
    edge_norm_k<<<((long)N_EDGES * NH + 255) / 256, 256, 0, stream>>>(ei, flag, ea, s_ws, anorm);
}